// Round 13
// baseline (438.444 us; speedup 1.0000x reference)
//
#include <hip/hip_runtime.h>
#include <math.h>

#define NT 1024
#define CD 2
#define DD 1024
#define GG 16
#define LOG1E6 -13.8155105579642740f
#define NEG_BIG -1e30f

typedef short bf16x8 __attribute__((ext_vector_type(8)));
typedef float f32x4  __attribute__((ext_vector_type(4)));

__device__ __forceinline__ unsigned short bf16_rne(float x) {
    unsigned int u = __float_as_uint(x);
    unsigned int r = (u + 0x7fffu + ((u >> 16) & 1u)) >> 16;
    return (unsigned short)r;
}

__device__ __forceinline__ void split3_8(const float* v, bf16x8& h, bf16x8& m, bf16x8& l) {
    #pragma unroll
    for (int e = 0; e < 8; ++e) {
        const float x = v[e];
        const unsigned short hb = bf16_rne(x);
        const float hf = __uint_as_float((unsigned int)hb << 16);
        const float r1 = x - hf;
        const unsigned short mb = bf16_rne(r1);
        const float mf = __uint_as_float((unsigned int)mb << 16);
        const float r2 = r1 - mf;
        const unsigned short lb = bf16_rne(r2);
        h[e] = (short)hb; m[e] = (short)mb; l[e] = (short)lb;
    }
}

// ---------------------------------------------------------------------------
// K0: pre-split fa / Wq / Wk / Wc into exact 3-way bf16 (h+m+l) arrays.
// ---------------------------------------------------------------------------
__global__ __launch_bounds__(256) void k0_split(
    const float* __restrict__ fa, const float* __restrict__ Wq,
    const float* __restrict__ Wk, const float* __restrict__ Wc,
    unsigned short* __restrict__ Fh, unsigned short* __restrict__ Fm, unsigned short* __restrict__ Fl,
    unsigned short* __restrict__ WQh, unsigned short* __restrict__ WQm, unsigned short* __restrict__ WQl,
    unsigned short* __restrict__ WKh, unsigned short* __restrict__ WKm, unsigned short* __restrict__ WKl,
    unsigned short* __restrict__ WCh, unsigned short* __restrict__ WCm, unsigned short* __restrict__ WCl)
{
    const int reg = blockIdx.y;
    const float* src = (reg == 0) ? fa : (reg == 1) ? Wq : (reg == 2) ? Wk : Wc;
    unsigned short* dh = (reg == 0) ? Fh : (reg == 1) ? WQh : (reg == 2) ? WKh : WCh;
    unsigned short* dm = (reg == 0) ? Fm : (reg == 1) ? WQm : (reg == 2) ? WKm : WCm;
    unsigned short* dl = (reg == 0) ? Fl : (reg == 1) ? WQl : (reg == 2) ? WKl : WCl;
    const int nv = (reg == 0) ? (1 << 19) : (1 << 18);   // float4 count

    for (int v = blockIdx.x * 256 + threadIdx.x; v < nv; v += gridDim.x * 256) {
        float4 x4 = *(const float4*)&src[(size_t)v * 4];
        float xv[4] = {x4.x, x4.y, x4.z, x4.w};
        ushort4 h4, m4, l4;
        unsigned short hv[4], mv[4], lv[4];
        #pragma unroll
        for (int q = 0; q < 4; ++q) {
            const float x = xv[q];
            const unsigned short hb = bf16_rne(x);
            const float hf = __uint_as_float((unsigned int)hb << 16);
            const float r1 = x - hf;
            const unsigned short mb = bf16_rne(r1);
            const float mf = __uint_as_float((unsigned int)mb << 16);
            const unsigned short lb = bf16_rne(r1 - mf);
            hv[q] = hb; mv[q] = mb; lv[q] = lb;
        }
        h4.x = hv[0]; h4.y = hv[1]; h4.z = hv[2]; h4.w = hv[3];
        m4.x = mv[0]; m4.y = mv[1]; m4.z = mv[2]; m4.w = mv[3];
        l4.x = lv[0]; l4.y = lv[1]; l4.z = lv[2]; l4.w = lv[3];
        *(ushort4*)&dh[(size_t)v * 4] = h4;
        *(ushort4*)&dm[(size_t)v * 4] = m4;
        *(ushort4*)&dl[(size_t)v * 4] = l4;
    }
}

// ---------------------------------------------------------------------------
// K1 v3 (R11/R12-validated): 6-term MFMA GEMM.  z==2 -> fp32 V out;
// z in {0,1} -> 3-way-split Q/K outputs for k2a_mfma.
// ---------------------------------------------------------------------------
__global__ __launch_bounds__(256) void k1_mfma(
    const unsigned short* __restrict__ Fh, const unsigned short* __restrict__ Fm,
    const unsigned short* __restrict__ Fl,
    const unsigned short* __restrict__ WQh, const unsigned short* __restrict__ WQm,
    const unsigned short* __restrict__ WQl,
    const unsigned short* __restrict__ WKh, const unsigned short* __restrict__ WKm,
    const unsigned short* __restrict__ WKl,
    const unsigned short* __restrict__ WCh, const unsigned short* __restrict__ WCm,
    const unsigned short* __restrict__ WCl,
    const float* __restrict__ bq, const float* __restrict__ bk, const float* __restrict__ bc,
    float* __restrict__ Vo,
    unsigned short* __restrict__ QSh, unsigned short* __restrict__ QSm, unsigned short* __restrict__ QSl,
    unsigned short* __restrict__ KSh, unsigned short* __restrict__ KSm, unsigned short* __restrict__ KSl)
{
    const int et = blockIdx.x, rt = blockIdx.y, z = blockIdx.z;
    const unsigned short* Wh = (z == 0) ? WQh : (z == 1) ? WKh : WCh;
    const unsigned short* Wm = (z == 0) ? WQm : (z == 1) ? WKm : WCm;
    const unsigned short* Wl = (z == 0) ? WQl : (z == 1) ? WKl : WCl;
    const float* bb = (z == 0) ? bq : (z == 1) ? bk : bc;
    unsigned short* Sh = (z == 0) ? QSh : KSh;
    unsigned short* Sm = (z == 0) ? QSm : KSm;
    unsigned short* Sl = (z == 0) ? QSl : KSl;

    const int c  = rt >> 3;
    const int n0 = (rt & 7) * 128;
    const int r0 = rt * 128;
    const int e0 = et * 64;

    __shared__ unsigned short Ah[128][36], Am[128][36], Al[128][36];
    __shared__ unsigned short Bh[64][36],  Bm[64][36],  Bl[64][36];

    const int t    = threadIdx.x;
    const int wave = t >> 6, lane = t & 63;
    const int wr   = wave >> 1, wc = wave & 1;
    const int lrow = lane & 15, lk = lane >> 4;

    f32x4 acc[4][2];
    #pragma unroll
    for (int m = 0; m < 4; ++m)
        #pragma unroll
        for (int n = 0; n < 2; ++n) acc[m][n] = (f32x4){0.f, 0.f, 0.f, 0.f};

    for (int kt = 0; kt < 32; ++kt) {
        const int kb = kt * 32;
        #pragma unroll
        for (int p = 0; p < 2; ++p) {
            const int task = t + p * 256;
            const int row = task >> 2, seg = task & 3;
            const size_t gs = ((size_t)((n0 + row) * CD + c)) * DD + kb + seg * 8;
            *(uint4*)&Ah[row][seg * 8] = *(const uint4*)&Fh[gs];
            *(uint4*)&Am[row][seg * 8] = *(const uint4*)&Fm[gs];
            *(uint4*)&Al[row][seg * 8] = *(const uint4*)&Fl[gs];
        }
        {
            const int row = t >> 2, seg = t & 3;
            const size_t gs = ((size_t)(e0 + row)) * DD + kb + seg * 8;
            *(uint4*)&Bh[row][seg * 8] = *(const uint4*)&Wh[gs];
            *(uint4*)&Bm[row][seg * 8] = *(const uint4*)&Wm[gs];
            *(uint4*)&Bl[row][seg * 8] = *(const uint4*)&Wl[gs];
        }
        __syncthreads();
        {
            bf16x8 ah[4], am[4], al[4], bh[2], bm[2], bl[2];
            #pragma unroll
            for (int m = 0; m < 4; ++m) {
                const int row = wr * 64 + m * 16 + lrow;
                ah[m] = *(const bf16x8*)&Ah[row][lk * 8];
                am[m] = *(const bf16x8*)&Am[row][lk * 8];
                al[m] = *(const bf16x8*)&Al[row][lk * 8];
            }
            #pragma unroll
            for (int n = 0; n < 2; ++n) {
                const int row = wc * 32 + n * 16 + lrow;
                bh[n] = *(const bf16x8*)&Bh[row][lk * 8];
                bm[n] = *(const bf16x8*)&Bm[row][lk * 8];
                bl[n] = *(const bf16x8*)&Bl[row][lk * 8];
            }
            #pragma unroll
            for (int m = 0; m < 4; ++m)
                #pragma unroll
                for (int n = 0; n < 2; ++n) {
                    acc[m][n] = __builtin_amdgcn_mfma_f32_16x16x32_bf16(al[m], bh[n], acc[m][n], 0, 0, 0);
                    acc[m][n] = __builtin_amdgcn_mfma_f32_16x16x32_bf16(ah[m], bl[n], acc[m][n], 0, 0, 0);
                    acc[m][n] = __builtin_amdgcn_mfma_f32_16x16x32_bf16(am[m], bm[n], acc[m][n], 0, 0, 0);
                    acc[m][n] = __builtin_amdgcn_mfma_f32_16x16x32_bf16(am[m], bh[n], acc[m][n], 0, 0, 0);
                    acc[m][n] = __builtin_amdgcn_mfma_f32_16x16x32_bf16(ah[m], bm[n], acc[m][n], 0, 0, 0);
                    acc[m][n] = __builtin_amdgcn_mfma_f32_16x16x32_bf16(ah[m], bh[n], acc[m][n], 0, 0, 0);
                }
        }
        __syncthreads();
    }
    #pragma unroll
    for (int n = 0; n < 2; ++n) {
        const int e = e0 + wc * 32 + n * 16 + lrow;
        const float bias = bb[e];
        #pragma unroll
        for (int m = 0; m < 4; ++m) {
            const int r = r0 + wr * 64 + m * 16 + lk * 4;
            #pragma unroll
            for (int q = 0; q < 4; ++q) {
                const float val = acc[m][n][q] + bias;
                const size_t idx = ((size_t)(r + q)) * DD + e;
                if (z == 2) {
                    Vo[idx] = val;
                } else {
                    const unsigned short hb = bf16_rne(val);
                    const float hf = __uint_as_float((unsigned int)hb << 16);
                    const float r1 = val - hf;
                    const unsigned short mb = bf16_rne(r1);
                    const float mf = __uint_as_float((unsigned int)mb << 16);
                    const unsigned short lb = bf16_rne(r1 - mf);
                    Sh[idx] = hb; Sm[idx] = mb; Sl[idx] = lb;
                }
            }
        }
    }
}

// ---------------------------------------------------------------------------
// K2a v3 (R12-validated): aff = Q.K^T/8 on the matrix pipe.
// ---------------------------------------------------------------------------
__global__ __launch_bounds__(256) void k2a_mfma(
    const unsigned short* __restrict__ QSh, const unsigned short* __restrict__ QSm,
    const unsigned short* __restrict__ QSl,
    const unsigned short* __restrict__ KSh, const unsigned short* __restrict__ KSm,
    const unsigned short* __restrict__ KSl,
    float* __restrict__ aff)
{
    const int jt = blockIdx.x, it = blockIdx.y, cg = blockIdx.z;
    const int c = cg >> 4, g = cg & 15;
    const int i0 = it * 64, j0 = jt * 64;

    __shared__ unsigned short Qh[64][36], Qm[64][36], Ql[64][36];
    __shared__ unsigned short Kh[64][36], Km[64][36], Kl[64][36];

    const int t    = threadIdx.x;
    const int wave = t >> 6, lane = t & 63;
    const int wr   = wave >> 1, wc = wave & 1;
    const int lrow = lane & 15, lk = lane >> 4;

    f32x4 acc[2][2];
    #pragma unroll
    for (int m = 0; m < 2; ++m)
        #pragma unroll
        for (int n = 0; n < 2; ++n) acc[m][n] = (f32x4){0.f, 0.f, 0.f, 0.f};

    for (int kt = 0; kt < 2; ++kt) {
        const int kb = g * 64 + kt * 32;
        {
            const int row = t >> 2, seg = t & 3;
            const size_t qs = ((size_t)(c * NT + i0 + row)) * DD + kb + seg * 8;
            *(uint4*)&Qh[row][seg * 8] = *(const uint4*)&QSh[qs];
            *(uint4*)&Qm[row][seg * 8] = *(const uint4*)&QSm[qs];
            *(uint4*)&Ql[row][seg * 8] = *(const uint4*)&QSl[qs];
            const size_t ks = ((size_t)(c * NT + j0 + row)) * DD + kb + seg * 8;
            *(uint4*)&Kh[row][seg * 8] = *(const uint4*)&KSh[ks];
            *(uint4*)&Km[row][seg * 8] = *(const uint4*)&KSm[ks];
            *(uint4*)&Kl[row][seg * 8] = *(const uint4*)&KSl[ks];
        }
        __syncthreads();
        {
            bf16x8 qh[2], qm[2], ql[2], kh[2], km[2], kl[2];
            #pragma unroll
            for (int m = 0; m < 2; ++m) {
                const int row = wr * 32 + m * 16 + lrow;
                qh[m] = *(const bf16x8*)&Qh[row][lk * 8];
                qm[m] = *(const bf16x8*)&Qm[row][lk * 8];
                ql[m] = *(const bf16x8*)&Ql[row][lk * 8];
            }
            #pragma unroll
            for (int n = 0; n < 2; ++n) {
                const int row = wc * 32 + n * 16 + lrow;
                kh[n] = *(const bf16x8*)&Kh[row][lk * 8];
                km[n] = *(const bf16x8*)&Km[row][lk * 8];
                kl[n] = *(const bf16x8*)&Kl[row][lk * 8];
            }
            #pragma unroll
            for (int m = 0; m < 2; ++m)
                #pragma unroll
                for (int n = 0; n < 2; ++n) {
                    acc[m][n] = __builtin_amdgcn_mfma_f32_16x16x32_bf16(ql[m], kh[n], acc[m][n], 0, 0, 0);
                    acc[m][n] = __builtin_amdgcn_mfma_f32_16x16x32_bf16(qh[m], kl[n], acc[m][n], 0, 0, 0);
                    acc[m][n] = __builtin_amdgcn_mfma_f32_16x16x32_bf16(qm[m], km[n], acc[m][n], 0, 0, 0);
                    acc[m][n] = __builtin_amdgcn_mfma_f32_16x16x32_bf16(qm[m], kh[n], acc[m][n], 0, 0, 0);
                    acc[m][n] = __builtin_amdgcn_mfma_f32_16x16x32_bf16(qh[m], km[n], acc[m][n], 0, 0, 0);
                    acc[m][n] = __builtin_amdgcn_mfma_f32_16x16x32_bf16(qh[m], kh[n], acc[m][n], 0, 0, 0);
                }
        }
        __syncthreads();
    }
    #pragma unroll
    for (int m = 0; m < 2; ++m) {
        const int i = i0 + wr * 32 + m * 16 + lk * 4;
        #pragma unroll
        for (int n = 0; n < 2; ++n) {
            const int j = j0 + wc * 32 + n * 16 + lrow;
            #pragma unroll
            for (int q = 0; q < 4; ++q)
                aff[((size_t)cg * NT + i + q) * NT + j] = acc[m][n][q] * 0.125f;
        }
    }
}

// ---------------------------------------------------------------------------
// K3 v5: BARRIER-FREE fused dense + top-10 scan.
//   One wave owns (c, i, 256-j chunk): 16 MFMA tiles (i fixed, 16 j x 16 g).
//   C-frag lane (lg,lk) holds 4 j for g=lg -> top-10 kept per-lane over its
//   lk-slice; aff/iou loaded directly per lane (float4); NO LDS, NO barriers.
//   End: 2-step __shfl merge (+32,+16) with tie-aware compare (lower index
//   wins, matching jax top_k), lanes 0..15 write final 10 per (c,i,g,ch).
//   Arithmetic identical to R12 (6-term split MFMA, log, add order).
// ---------------------------------------------------------------------------
__global__ __launch_bounds__(256, 5) void k3_scan(
    const float* __restrict__ pe, const float* __restrict__ iou,
    const float* __restrict__ WGw, const float* __restrict__ WGb,
    const float* __restrict__ aff,
    float* __restrict__ cv, int* __restrict__ ci)
{
    const int ch = blockIdx.x;               // 0..3 (256 j each)
    const int c  = blockIdx.z;
    const int wave = threadIdx.x >> 6, lane = threadIdx.x & 63;
    const int i  = blockIdx.y * 4 + wave;    // 0..1023
    const int lg = lane & 15, lk = lane >> 4;

    // B-frags: WGw split 3-way, register-resident (R9-validated mapping)
    bf16x8 bh[2], bm[2], bl[2];
    #pragma unroll
    for (int kp = 0; kp < 2; ++kp) {
        float w8[8];
        float4 w0 = *(const float4*)&WGw[lg * 64 + kp * 32 + lk * 8];
        float4 w1 = *(const float4*)&WGw[lg * 64 + kp * 32 + lk * 8 + 4];
        w8[0]=w0.x; w8[1]=w0.y; w8[2]=w0.z; w8[3]=w0.w;
        w8[4]=w1.x; w8[5]=w1.y; w8[6]=w1.z; w8[7]=w1.w;
        split3_8(w8, bh[kp], bm[kp], bl[kp]);
    }
    const float bias = WGb[lg];

    float tv[10]; int tidx[10];
    #pragma unroll
    for (int q = 0; q < 10; ++q) { tv[q] = NEG_BIG; tidx[q] = 0; }

    const float* pebase = &pe[((size_t)c * NT + i) * NT * 64];
    const float* afrow  = &aff[(((size_t)(c * GG + lg)) * NT + i) * NT];
    const float* iorow  = &iou[((size_t)c * NT + i) * NT];

    #pragma unroll 1
    for (int tile = 0; tile < 16; ++tile) {
        const int jb = ch * 256 + tile * 16;
        // A = pe rows j=jb+lg (lane&15 indexes the A-row = j)
        const float* pr = &pebase[(size_t)(jb + lg) * 64];
        f32x4 acc = {0.f, 0.f, 0.f, 0.f};
        #pragma unroll
        for (int kp = 0; kp < 2; ++kp) {
            float a8[8];
            float4 v0 = *(const float4*)&pr[kp * 32 + lk * 8];
            float4 v1 = *(const float4*)&pr[kp * 32 + lk * 8 + 4];
            a8[0]=v0.x; a8[1]=v0.y; a8[2]=v0.z; a8[3]=v0.w;
            a8[4]=v1.x; a8[5]=v1.y; a8[6]=v1.z; a8[7]=v1.w;
            bf16x8 ah, am, al;
            split3_8(a8, ah, am, al);
            acc = __builtin_amdgcn_mfma_f32_16x16x32_bf16(al, bh[kp], acc, 0, 0, 0);
            acc = __builtin_amdgcn_mfma_f32_16x16x32_bf16(ah, bl[kp], acc, 0, 0, 0);
            acc = __builtin_amdgcn_mfma_f32_16x16x32_bf16(am, bm[kp], acc, 0, 0, 0);
            acc = __builtin_amdgcn_mfma_f32_16x16x32_bf16(am, bh[kp], acc, 0, 0, 0);
            acc = __builtin_amdgcn_mfma_f32_16x16x32_bf16(ah, bm[kp], acc, 0, 0, 0);
            acc = __builtin_amdgcn_mfma_f32_16x16x32_bf16(ah, bh[kp], acc, 0, 0, 0);
        }
        // C-frag: lane (lg,lk) holds j = jb + lk*4 + q for g = lg  [m89]
        float4 a4 = *(const float4*)&afrow[jb + lk * 4];
        float4 o4 = *(const float4*)&iorow[jb + lk * 4];
        float av[4] = {a4.x, a4.y, a4.z, a4.w};
        float ov[4] = {o4.x, o4.y, o4.z, o4.w};
        #pragma unroll
        for (int q = 0; q < 4; ++q) {
            const float wg = acc[q] + bias;
            const float lgv = (wg > 1e-6f) ? __logf(wg) : LOG1E6;
            const float val = lgv + av[q] + ((ov[q] >= 1e-6f) ? 0.f : LOG1E6);
            if (val > tv[0]) {                       // in-lane: j strictly ascending
                const int ix = jb + lk * 4 + q;
                #pragma unroll
                for (int sl = 0; sl < 10; ++sl) {
                    const bool up   = (sl < 9) ? (val > tv[sl + 1]) : false;
                    const bool here = (val > tv[sl]);
                    const float ntv = up ? tv[sl + 1] : (here ? val : tv[sl]);
                    const int   nti = up ? tidx[sl + 1] : (here ? ix : tidx[sl]);
                    tv[sl] = ntv; tidx[sl] = nti;
                }
            }
        }
    }

    // cross-lane merge over lk (tie-aware: equal val -> lower j wins, = jax)
    #pragma unroll
    for (int step = 0; step < 2; ++step) {
        const int ofs = (step == 0) ? 32 : 16;
        float otv[10]; int oti[10];
        #pragma unroll
        for (int q = 0; q < 10; ++q) {
            otv[q] = __shfl(tv[q], lane + ofs);
            oti[q] = __shfl(tidx[q], lane + ofs);
        }
        #pragma unroll
        for (int q = 9; q >= 0; --q) {
            const float ov = otv[q]; const int oi = oti[q];
            const bool g0 = (ov > tv[0]) || (ov == tv[0] && oi < tidx[0]);
            if (g0) {
                #pragma unroll
                for (int sl = 0; sl < 10; ++sl) {
                    const bool up   = (sl < 9) ? ((ov > tv[sl + 1]) || (ov == tv[sl + 1] && oi < tidx[sl + 1])) : false;
                    const bool here = (ov > tv[sl]) || (ov == tv[sl] && oi < tidx[sl]);
                    const float ntv = up ? tv[sl + 1] : (here ? ov : tv[sl]);
                    const int   nti = up ? tidx[sl + 1] : (here ? oi : tidx[sl]);
                    tv[sl] = ntv; tidx[sl] = nti;
                }
            }
        }
    }

    if (lane < 16) {   // lane = g
        const size_t base = ((((size_t)c * NT + i) * GG + lane) * 4 + ch) * 10;
        #pragma unroll
        for (int q = 0; q < 10; ++q) { cv[base + q] = tv[q]; ci[base + q] = tidx[q]; }
    }
}

// ---------------------------------------------------------------------------
// K2b2 (unchanged): per-(c,i,g) wave merge + softmax + coalesced V-gather.
// ---------------------------------------------------------------------------
__global__ __launch_bounds__(256) void k2b2_fin(
    const float* __restrict__ cv, const int* __restrict__ ci,
    const float* __restrict__ V, float* __restrict__ y)
{
    const int w    = (blockIdx.x << 2) + (threadIdx.x >> 6);
    const int lane = threadIdx.x & 63;
    const int c = w >> 14;
    const int i = (w >> 4) & (NT - 1);
    const int g = w & 15;

    float tv[10]; int tidx[10];
    #pragma unroll
    for (int q = 0; q < 10; ++q) { tv[q] = NEG_BIG; tidx[q] = 0; }

    const size_t base = (size_t)w * 40;
    for (int chn = 0; chn < 4; ++chn) {
        const float* cvp = &cv[base + chn * 10];
        const int*   cip = &ci[base + chn * 10];
        for (int q = 9; q >= 0; --q) {
            const float val = cvp[q];
            const int   ix  = cip[q];
            if (val > tv[0]) {
                #pragma unroll
                for (int sl = 0; sl < 10; ++sl) {
                    const bool up   = (sl < 9) ? (val > tv[sl + 1]) : false;
                    const bool here = (val > tv[sl]);
                    const float ntv = up ? tv[sl + 1] : (here ? val : tv[sl]);
                    const int   nti = up ? tidx[sl + 1] : (here ? ix : tidx[sl]);
                    tv[sl] = ntv; tidx[sl] = nti;
                }
            }
        }
    }
    const float m = tv[9];
    float wgt[10]; float sm = 0.f;
    #pragma unroll
    for (int q = 0; q < 10; ++q) { wgt[q] = __expf(tv[q] - m); sm += wgt[q]; }
    const float inv = 1.f / sm;
    float o = 0.f;
    #pragma unroll
    for (int q = 0; q < 10; ++q)
        o += (wgt[q] * inv) * V[((size_t)(c * NT + tidx[q])) * DD + g * 64 + lane];
    y[((size_t)i * CD + c) * DD + g * 64 + lane] = o;
}

extern "C" void kernel_launch(void* const* d_in, const int* in_sizes, int n_in,
                              void* d_out, int out_size, void* d_ws, size_t ws_size,
                              hipStream_t stream) {
    (void)in_sizes; (void)n_in; (void)out_size; (void)ws_size;
    const float* f_a = (const float*)d_in[0];
    const float* pe  = (const float*)d_in[1];
    const float* iou = (const float*)d_in[2];
    const float* WGw = (const float*)d_in[3];
    const float* WGb = (const float*)d_in[4];
    const float* WKw = (const float*)d_in[5];
    const float* WKb = (const float*)d_in[6];
    const float* WQw = (const float*)d_in[7];
    const float* WQb = (const float*)d_in[8];
    const float* Cw  = (const float*)d_in[9];
    const float* Cb  = (const float*)d_in[10];
    float* yout = (float*)d_out;

    float* ws  = (float*)d_ws;
    float* V   = ws + (2u << 21);
    float* aff = ws + (3u << 21);
    float* cv  = ws;
    int*   ci  = (int*)(ws + (1u << 21));
    unsigned short* sp = (unsigned short*)(ws + (3u << 21) + (1u << 25));
    const size_t FN = (size_t)CD * NT * DD;   // 2M
    const size_t WN = (size_t)DD * DD;        // 1M
    unsigned short* Fh  = sp;
    unsigned short* Fm  = Fh + FN;
    unsigned short* Fl  = Fm + FN;
    unsigned short* WQh = Fl + FN;
    unsigned short* WQm = WQh + WN;
    unsigned short* WQl = WQm + WN;
    unsigned short* WKh = WQl + WN;
    unsigned short* WKm = WKh + WN;
    unsigned short* WKl = WKm + WN;
    unsigned short* WCh = WKl + WN;
    unsigned short* WCm = WCh + WN;
    unsigned short* WCl = WCm + WN;
    unsigned short* QSh = WCl + WN;
    unsigned short* QSm = QSh + FN;
    unsigned short* QSl = QSm + FN;
    unsigned short* KSh = QSl + FN;
    unsigned short* KSm = KSh + FN;
    unsigned short* KSl = KSm + FN;

    k0_split<<<dim3(512, 4), 256, 0, stream>>>(f_a, WQw, WKw, Cw,
        Fh, Fm, Fl, WQh, WQm, WQl, WKh, WKm, WKl, WCh, WCm, WCl);
    k1_mfma<<<dim3(16, 16, 3), 256, 0, stream>>>(
        Fh, Fm, Fl, WQh, WQm, WQl, WKh, WKm, WKl, WCh, WCm, WCl,
        WQb, WKb, Cb, V, QSh, QSm, QSl, KSh, KSm, KSl);
    k2a_mfma<<<dim3(16, 16, 32), 256, 0, stream>>>(QSh, QSm, QSl, KSh, KSm, KSl, aff);
    k3_scan<<<dim3(4, 256, 2), 256, 0, stream>>>(pe, iou, WGw, WGb, aff, cv, ci);
    k2b2_fin<<<8192, 256, 0, stream>>>(cv, ci, V, yout);
}

// Round 14
// 426.652 us; speedup vs baseline: 1.0276x; 1.0276x over previous
//
#include <hip/hip_runtime.h>
#include <math.h>

#define NT 1024
#define CD 2
#define DD 1024
#define GG 16
#define LOG1E6 -13.8155105579642740f
#define NEG_BIG -1e30f

typedef short bf16x8 __attribute__((ext_vector_type(8)));
typedef float f32x4  __attribute__((ext_vector_type(4)));

__device__ __forceinline__ unsigned short bf16_rne(float x) {
    unsigned int u = __float_as_uint(x);
    unsigned int r = (u + 0x7fffu + ((u >> 16) & 1u)) >> 16;
    return (unsigned short)r;
}

__device__ __forceinline__ void split3_8(const float* v, bf16x8& h, bf16x8& m, bf16x8& l) {
    #pragma unroll
    for (int e = 0; e < 8; ++e) {
        const float x = v[e];
        const unsigned short hb = bf16_rne(x);
        const float hf = __uint_as_float((unsigned int)hb << 16);
        const float r1 = x - hf;
        const unsigned short mb = bf16_rne(r1);
        const float mf = __uint_as_float((unsigned int)mb << 16);
        const float r2 = r1 - mf;
        const unsigned short lb = bf16_rne(r2);
        h[e] = (short)hb; m[e] = (short)mb; l[e] = (short)lb;
    }
}

// ---------------------------------------------------------------------------
// K0: pre-split fa / Wq / Wk / Wc into exact 3-way bf16 (h+m+l) arrays.
// ---------------------------------------------------------------------------
__global__ __launch_bounds__(256) void k0_split(
    const float* __restrict__ fa, const float* __restrict__ Wq,
    const float* __restrict__ Wk, const float* __restrict__ Wc,
    unsigned short* __restrict__ Fh, unsigned short* __restrict__ Fm, unsigned short* __restrict__ Fl,
    unsigned short* __restrict__ WQh, unsigned short* __restrict__ WQm, unsigned short* __restrict__ WQl,
    unsigned short* __restrict__ WKh, unsigned short* __restrict__ WKm, unsigned short* __restrict__ WKl,
    unsigned short* __restrict__ WCh, unsigned short* __restrict__ WCm, unsigned short* __restrict__ WCl)
{
    const int reg = blockIdx.y;
    const float* src = (reg == 0) ? fa : (reg == 1) ? Wq : (reg == 2) ? Wk : Wc;
    unsigned short* dh = (reg == 0) ? Fh : (reg == 1) ? WQh : (reg == 2) ? WKh : WCh;
    unsigned short* dm = (reg == 0) ? Fm : (reg == 1) ? WQm : (reg == 2) ? WKm : WCm;
    unsigned short* dl = (reg == 0) ? Fl : (reg == 1) ? WQl : (reg == 2) ? WKl : WCl;
    const int nv = (reg == 0) ? (1 << 19) : (1 << 18);   // float4 count

    for (int v = blockIdx.x * 256 + threadIdx.x; v < nv; v += gridDim.x * 256) {
        float4 x4 = *(const float4*)&src[(size_t)v * 4];
        float xv[4] = {x4.x, x4.y, x4.z, x4.w};
        ushort4 h4, m4, l4;
        unsigned short hv[4], mv[4], lv[4];
        #pragma unroll
        for (int q = 0; q < 4; ++q) {
            const float x = xv[q];
            const unsigned short hb = bf16_rne(x);
            const float hf = __uint_as_float((unsigned int)hb << 16);
            const float r1 = x - hf;
            const unsigned short mb = bf16_rne(r1);
            const float mf = __uint_as_float((unsigned int)mb << 16);
            const unsigned short lb = bf16_rne(r1 - mf);
            hv[q] = hb; mv[q] = mb; lv[q] = lb;
        }
        h4.x = hv[0]; h4.y = hv[1]; h4.z = hv[2]; h4.w = hv[3];
        m4.x = mv[0]; m4.y = mv[1]; m4.z = mv[2]; m4.w = mv[3];
        l4.x = lv[0]; l4.y = lv[1]; l4.z = lv[2]; l4.w = lv[3];
        *(ushort4*)&dh[(size_t)v * 4] = h4;
        *(ushort4*)&dm[(size_t)v * 4] = m4;
        *(ushort4*)&dl[(size_t)v * 4] = l4;
    }
}

// ---------------------------------------------------------------------------
// K1 v3 (R11/R12-validated): 6-term MFMA GEMM.  z==2 -> fp32 V out;
// z in {0,1} -> 3-way-split Q/K outputs for k2a_mfma.
// ---------------------------------------------------------------------------
__global__ __launch_bounds__(256) void k1_mfma(
    const unsigned short* __restrict__ Fh, const unsigned short* __restrict__ Fm,
    const unsigned short* __restrict__ Fl,
    const unsigned short* __restrict__ WQh, const unsigned short* __restrict__ WQm,
    const unsigned short* __restrict__ WQl,
    const unsigned short* __restrict__ WKh, const unsigned short* __restrict__ WKm,
    const unsigned short* __restrict__ WKl,
    const unsigned short* __restrict__ WCh, const unsigned short* __restrict__ WCm,
    const unsigned short* __restrict__ WCl,
    const float* __restrict__ bq, const float* __restrict__ bk, const float* __restrict__ bc,
    float* __restrict__ Vo,
    unsigned short* __restrict__ QSh, unsigned short* __restrict__ QSm, unsigned short* __restrict__ QSl,
    unsigned short* __restrict__ KSh, unsigned short* __restrict__ KSm, unsigned short* __restrict__ KSl)
{
    const int et = blockIdx.x, rt = blockIdx.y, z = blockIdx.z;
    const unsigned short* Wh = (z == 0) ? WQh : (z == 1) ? WKh : WCh;
    const unsigned short* Wm = (z == 0) ? WQm : (z == 1) ? WKm : WCm;
    const unsigned short* Wl = (z == 0) ? WQl : (z == 1) ? WKl : WCl;
    const float* bb = (z == 0) ? bq : (z == 1) ? bk : bc;
    unsigned short* Sh = (z == 0) ? QSh : KSh;
    unsigned short* Sm = (z == 0) ? QSm : KSm;
    unsigned short* Sl = (z == 0) ? QSl : KSl;

    const int c  = rt >> 3;
    const int n0 = (rt & 7) * 128;
    const int r0 = rt * 128;
    const int e0 = et * 64;

    __shared__ unsigned short Ah[128][36], Am[128][36], Al[128][36];
    __shared__ unsigned short Bh[64][36],  Bm[64][36],  Bl[64][36];

    const int t    = threadIdx.x;
    const int wave = t >> 6, lane = t & 63;
    const int wr   = wave >> 1, wc = wave & 1;
    const int lrow = lane & 15, lk = lane >> 4;

    f32x4 acc[4][2];
    #pragma unroll
    for (int m = 0; m < 4; ++m)
        #pragma unroll
        for (int n = 0; n < 2; ++n) acc[m][n] = (f32x4){0.f, 0.f, 0.f, 0.f};

    for (int kt = 0; kt < 32; ++kt) {
        const int kb = kt * 32;
        #pragma unroll
        for (int p = 0; p < 2; ++p) {
            const int task = t + p * 256;
            const int row = task >> 2, seg = task & 3;
            const size_t gs = ((size_t)((n0 + row) * CD + c)) * DD + kb + seg * 8;
            *(uint4*)&Ah[row][seg * 8] = *(const uint4*)&Fh[gs];
            *(uint4*)&Am[row][seg * 8] = *(const uint4*)&Fm[gs];
            *(uint4*)&Al[row][seg * 8] = *(const uint4*)&Fl[gs];
        }
        {
            const int row = t >> 2, seg = t & 3;
            const size_t gs = ((size_t)(e0 + row)) * DD + kb + seg * 8;
            *(uint4*)&Bh[row][seg * 8] = *(const uint4*)&Wh[gs];
            *(uint4*)&Bm[row][seg * 8] = *(const uint4*)&Wm[gs];
            *(uint4*)&Bl[row][seg * 8] = *(const uint4*)&Wl[gs];
        }
        __syncthreads();
        {
            bf16x8 ah[4], am[4], al[4], bh[2], bm[2], bl[2];
            #pragma unroll
            for (int m = 0; m < 4; ++m) {
                const int row = wr * 64 + m * 16 + lrow;
                ah[m] = *(const bf16x8*)&Ah[row][lk * 8];
                am[m] = *(const bf16x8*)&Am[row][lk * 8];
                al[m] = *(const bf16x8*)&Al[row][lk * 8];
            }
            #pragma unroll
            for (int n = 0; n < 2; ++n) {
                const int row = wc * 32 + n * 16 + lrow;
                bh[n] = *(const bf16x8*)&Bh[row][lk * 8];
                bm[n] = *(const bf16x8*)&Bm[row][lk * 8];
                bl[n] = *(const bf16x8*)&Bl[row][lk * 8];
            }
            #pragma unroll
            for (int m = 0; m < 4; ++m)
                #pragma unroll
                for (int n = 0; n < 2; ++n) {
                    acc[m][n] = __builtin_amdgcn_mfma_f32_16x16x32_bf16(al[m], bh[n], acc[m][n], 0, 0, 0);
                    acc[m][n] = __builtin_amdgcn_mfma_f32_16x16x32_bf16(ah[m], bl[n], acc[m][n], 0, 0, 0);
                    acc[m][n] = __builtin_amdgcn_mfma_f32_16x16x32_bf16(am[m], bm[n], acc[m][n], 0, 0, 0);
                    acc[m][n] = __builtin_amdgcn_mfma_f32_16x16x32_bf16(am[m], bh[n], acc[m][n], 0, 0, 0);
                    acc[m][n] = __builtin_amdgcn_mfma_f32_16x16x32_bf16(ah[m], bm[n], acc[m][n], 0, 0, 0);
                    acc[m][n] = __builtin_amdgcn_mfma_f32_16x16x32_bf16(ah[m], bh[n], acc[m][n], 0, 0, 0);
                }
        }
        __syncthreads();
    }
    #pragma unroll
    for (int n = 0; n < 2; ++n) {
        const int e = e0 + wc * 32 + n * 16 + lrow;
        const float bias = bb[e];
        #pragma unroll
        for (int m = 0; m < 4; ++m) {
            const int r = r0 + wr * 64 + m * 16 + lk * 4;
            #pragma unroll
            for (int q = 0; q < 4; ++q) {
                const float val = acc[m][n][q] + bias;
                const size_t idx = ((size_t)(r + q)) * DD + e;
                if (z == 2) {
                    Vo[idx] = val;
                } else {
                    const unsigned short hb = bf16_rne(val);
                    const float hf = __uint_as_float((unsigned int)hb << 16);
                    const float r1 = val - hf;
                    const unsigned short mb = bf16_rne(r1);
                    const float mf = __uint_as_float((unsigned int)mb << 16);
                    const unsigned short lb = bf16_rne(r1 - mf);
                    Sh[idx] = hb; Sm[idx] = mb; Sl[idx] = lb;
                }
            }
        }
    }
}

// ---------------------------------------------------------------------------
// K2a v3 (R12-validated): aff = Q.K^T/8 on the matrix pipe.
// ---------------------------------------------------------------------------
__global__ __launch_bounds__(256) void k2a_mfma(
    const unsigned short* __restrict__ QSh, const unsigned short* __restrict__ QSm,
    const unsigned short* __restrict__ QSl,
    const unsigned short* __restrict__ KSh, const unsigned short* __restrict__ KSm,
    const unsigned short* __restrict__ KSl,
    float* __restrict__ aff)
{
    const int jt = blockIdx.x, it = blockIdx.y, cg = blockIdx.z;
    const int c = cg >> 4, g = cg & 15;
    const int i0 = it * 64, j0 = jt * 64;

    __shared__ unsigned short Qh[64][36], Qm[64][36], Ql[64][36];
    __shared__ unsigned short Kh[64][36], Km[64][36], Kl[64][36];

    const int t    = threadIdx.x;
    const int wave = t >> 6, lane = t & 63;
    const int wr   = wave >> 1, wc = wave & 1;
    const int lrow = lane & 15, lk = lane >> 4;

    f32x4 acc[2][2];
    #pragma unroll
    for (int m = 0; m < 2; ++m)
        #pragma unroll
        for (int n = 0; n < 2; ++n) acc[m][n] = (f32x4){0.f, 0.f, 0.f, 0.f};

    for (int kt = 0; kt < 2; ++kt) {
        const int kb = g * 64 + kt * 32;
        {
            const int row = t >> 2, seg = t & 3;
            const size_t qs = ((size_t)(c * NT + i0 + row)) * DD + kb + seg * 8;
            *(uint4*)&Qh[row][seg * 8] = *(const uint4*)&QSh[qs];
            *(uint4*)&Qm[row][seg * 8] = *(const uint4*)&QSm[qs];
            *(uint4*)&Ql[row][seg * 8] = *(const uint4*)&QSl[qs];
            const size_t ks = ((size_t)(c * NT + j0 + row)) * DD + kb + seg * 8;
            *(uint4*)&Kh[row][seg * 8] = *(const uint4*)&KSh[ks];
            *(uint4*)&Km[row][seg * 8] = *(const uint4*)&KSm[ks];
            *(uint4*)&Kl[row][seg * 8] = *(const uint4*)&KSl[ks];
        }
        __syncthreads();
        {
            bf16x8 qh[2], qm[2], ql[2], kh[2], km[2], kl[2];
            #pragma unroll
            for (int m = 0; m < 2; ++m) {
                const int row = wr * 32 + m * 16 + lrow;
                qh[m] = *(const bf16x8*)&Qh[row][lk * 8];
                qm[m] = *(const bf16x8*)&Qm[row][lk * 8];
                ql[m] = *(const bf16x8*)&Ql[row][lk * 8];
            }
            #pragma unroll
            for (int n = 0; n < 2; ++n) {
                const int row = wc * 32 + n * 16 + lrow;
                kh[n] = *(const bf16x8*)&Kh[row][lk * 8];
                km[n] = *(const bf16x8*)&Km[row][lk * 8];
                kl[n] = *(const bf16x8*)&Kl[row][lk * 8];
            }
            #pragma unroll
            for (int m = 0; m < 2; ++m)
                #pragma unroll
                for (int n = 0; n < 2; ++n) {
                    acc[m][n] = __builtin_amdgcn_mfma_f32_16x16x32_bf16(ql[m], kh[n], acc[m][n], 0, 0, 0);
                    acc[m][n] = __builtin_amdgcn_mfma_f32_16x16x32_bf16(qh[m], kl[n], acc[m][n], 0, 0, 0);
                    acc[m][n] = __builtin_amdgcn_mfma_f32_16x16x32_bf16(qm[m], km[n], acc[m][n], 0, 0, 0);
                    acc[m][n] = __builtin_amdgcn_mfma_f32_16x16x32_bf16(qm[m], kh[n], acc[m][n], 0, 0, 0);
                    acc[m][n] = __builtin_amdgcn_mfma_f32_16x16x32_bf16(qh[m], km[n], acc[m][n], 0, 0, 0);
                    acc[m][n] = __builtin_amdgcn_mfma_f32_16x16x32_bf16(qh[m], kh[n], acc[m][n], 0, 0, 0);
                }
        }
        __syncthreads();
    }
    #pragma unroll
    for (int m = 0; m < 2; ++m) {
        const int i = i0 + wr * 32 + m * 16 + lk * 4;
        #pragma unroll
        for (int n = 0; n < 2; ++n) {
            const int j = j0 + wc * 32 + n * 16 + lrow;
            #pragma unroll
            for (int q = 0; q < 4; ++q)
                aff[((size_t)cg * NT + i + q) * NT + j] = acc[m][n][q] * 0.125f;
        }
    }
}

// ---------------------------------------------------------------------------
// K3 v6: barrier-free fused dense + top-10 scan (R13 skeleton), fixed:
//   (1) __launch_bounds__(256,4): 128-VGPR cap, no spill (R13's (256,5)
//       cap ~100 was at/over the ~120 live set -> suspected scratch spill).
//   (2) 1-tile-ahead explicit prefetch of pe/aff/iou: next-tile loads are
//       issued BEFORE current tile's split+MFMA+scan, so ~600cy HBM latency
//       hides under ~500cy of per-tile compute (plus wave TLP).
//   Next-tile index (tile+1)&15 keeps addresses in-bounds (tile 15 re-reads
//   tile 0: L1-hot, harmless) and the branch uniform.
//   Scan + tie-aware shfl merge identical to R13 (correctness validated).
// ---------------------------------------------------------------------------
__global__ __launch_bounds__(256, 4) void k3_scan(
    const float* __restrict__ pe, const float* __restrict__ iou,
    const float* __restrict__ WGw, const float* __restrict__ WGb,
    const float* __restrict__ aff,
    float* __restrict__ cv, int* __restrict__ ci)
{
    const int ch = blockIdx.x;               // 0..3 (256 j each)
    const int c  = blockIdx.z;
    const int wave = threadIdx.x >> 6, lane = threadIdx.x & 63;
    const int i  = blockIdx.y * 4 + wave;    // 0..1023
    const int lg = lane & 15, lk = lane >> 4;

    // B-frags: WGw split 3-way, register-resident (R9-validated mapping)
    bf16x8 bh[2], bm[2], bl[2];
    #pragma unroll
    for (int kp = 0; kp < 2; ++kp) {
        float w8[8];
        float4 w0 = *(const float4*)&WGw[lg * 64 + kp * 32 + lk * 8];
        float4 w1 = *(const float4*)&WGw[lg * 64 + kp * 32 + lk * 8 + 4];
        w8[0]=w0.x; w8[1]=w0.y; w8[2]=w0.z; w8[3]=w0.w;
        w8[4]=w1.x; w8[5]=w1.y; w8[6]=w1.z; w8[7]=w1.w;
        split3_8(w8, bh[kp], bm[kp], bl[kp]);
    }
    const float bias = WGb[lg];

    float tv[10]; int tidx[10];
    #pragma unroll
    for (int q = 0; q < 10; ++q) { tv[q] = NEG_BIG; tidx[q] = 0; }

    const float* pebase = &pe[((size_t)c * NT + i) * NT * 64];
    const float* afrow  = &aff[(((size_t)(c * GG + lg)) * NT + i) * NT];
    const float* iorow  = &iou[((size_t)c * NT + i) * NT];
    const int jb0 = ch * 256;

    // prime tile 0
    float4 pv0[2], pv1[2], pa4, po4;
    {
        const float* pr = &pebase[(size_t)(jb0 + lg) * 64];
        pv0[0] = *(const float4*)&pr[lk * 8];
        pv1[0] = *(const float4*)&pr[lk * 8 + 4];
        pv0[1] = *(const float4*)&pr[32 + lk * 8];
        pv1[1] = *(const float4*)&pr[32 + lk * 8 + 4];
        pa4 = *(const float4*)&afrow[jb0 + lk * 4];
        po4 = *(const float4*)&iorow[jb0 + lk * 4];
    }

    #pragma unroll 1
    for (int tile = 0; tile < 16; ++tile) {
        const int jb = jb0 + tile * 16;
        // ---- issue next-tile loads first (hide HBM latency under compute) ----
        float4 nv0[2], nv1[2], na4, no4;
        {
            const int njb = jb0 + ((tile + 1) & 15) * 16;
            const float* nr = &pebase[(size_t)(njb + lg) * 64];
            nv0[0] = *(const float4*)&nr[lk * 8];
            nv1[0] = *(const float4*)&nr[lk * 8 + 4];
            nv0[1] = *(const float4*)&nr[32 + lk * 8];
            nv1[1] = *(const float4*)&nr[32 + lk * 8 + 4];
            na4 = *(const float4*)&afrow[njb + lk * 4];
            no4 = *(const float4*)&iorow[njb + lk * 4];
        }
        // ---- compute current tile: split + 12 MFMA ----
        f32x4 acc = {0.f, 0.f, 0.f, 0.f};
        #pragma unroll
        for (int kp = 0; kp < 2; ++kp) {
            float a8[8];
            a8[0]=pv0[kp].x; a8[1]=pv0[kp].y; a8[2]=pv0[kp].z; a8[3]=pv0[kp].w;
            a8[4]=pv1[kp].x; a8[5]=pv1[kp].y; a8[6]=pv1[kp].z; a8[7]=pv1[kp].w;
            bf16x8 ah, am, al;
            split3_8(a8, ah, am, al);
            acc = __builtin_amdgcn_mfma_f32_16x16x32_bf16(al, bh[kp], acc, 0, 0, 0);
            acc = __builtin_amdgcn_mfma_f32_16x16x32_bf16(ah, bl[kp], acc, 0, 0, 0);
            acc = __builtin_amdgcn_mfma_f32_16x16x32_bf16(am, bm[kp], acc, 0, 0, 0);
            acc = __builtin_amdgcn_mfma_f32_16x16x32_bf16(am, bh[kp], acc, 0, 0, 0);
            acc = __builtin_amdgcn_mfma_f32_16x16x32_bf16(ah, bm[kp], acc, 0, 0, 0);
            acc = __builtin_amdgcn_mfma_f32_16x16x32_bf16(ah, bh[kp], acc, 0, 0, 0);
        }
        // ---- scan current tile (C-frag: lane (lg,lk) holds j=jb+lk*4+q, g=lg) ----
        float av[4] = {pa4.x, pa4.y, pa4.z, pa4.w};
        float ov[4] = {po4.x, po4.y, po4.z, po4.w};
        #pragma unroll
        for (int q = 0; q < 4; ++q) {
            const float wg = acc[q] + bias;
            const float lgv = (wg > 1e-6f) ? __logf(wg) : LOG1E6;
            const float val = lgv + av[q] + ((ov[q] >= 1e-6f) ? 0.f : LOG1E6);
            if (val > tv[0]) {
                const int ix = jb + lk * 4 + q;
                #pragma unroll
                for (int sl = 0; sl < 10; ++sl) {
                    const bool up   = (sl < 9) ? (val > tv[sl + 1]) : false;
                    const bool here = (val > tv[sl]);
                    const float ntv = up ? tv[sl + 1] : (here ? val : tv[sl]);
                    const int   nti = up ? tidx[sl + 1] : (here ? ix : tidx[sl]);
                    tv[sl] = ntv; tidx[sl] = nti;
                }
            }
        }
        // ---- rotate prefetch ----
        pv0[0] = nv0[0]; pv0[1] = nv0[1];
        pv1[0] = nv1[0]; pv1[1] = nv1[1];
        pa4 = na4; po4 = no4;
    }

    // cross-lane merge over lk (tie-aware: equal val -> lower j wins, = jax)
    #pragma unroll
    for (int step = 0; step < 2; ++step) {
        const int ofs = (step == 0) ? 32 : 16;
        float otv[10]; int oti[10];
        #pragma unroll
        for (int q = 0; q < 10; ++q) {
            otv[q] = __shfl(tv[q], lane + ofs);
            oti[q] = __shfl(tidx[q], lane + ofs);
        }
        #pragma unroll
        for (int q = 9; q >= 0; --q) {
            const float ov = otv[q]; const int oi = oti[q];
            const bool g0 = (ov > tv[0]) || (ov == tv[0] && oi < tidx[0]);
            if (g0) {
                #pragma unroll
                for (int sl = 0; sl < 10; ++sl) {
                    const bool up   = (sl < 9) ? ((ov > tv[sl + 1]) || (ov == tv[sl + 1] && oi < tidx[sl + 1])) : false;
                    const bool here = (ov > tv[sl]) || (ov == tv[sl] && oi < tidx[sl]);
                    const float ntv = up ? tv[sl + 1] : (here ? ov : tv[sl]);
                    const int   nti = up ? tidx[sl + 1] : (here ? oi : tidx[sl]);
                    tv[sl] = ntv; tidx[sl] = nti;
                }
            }
        }
    }

    if (lane < 16) {   // lane = g
        const size_t base = ((((size_t)c * NT + i) * GG + lane) * 4 + ch) * 10;
        #pragma unroll
        for (int q = 0; q < 10; ++q) { cv[base + q] = tv[q]; ci[base + q] = tidx[q]; }
    }
}

// ---------------------------------------------------------------------------
// K2b2 (unchanged): per-(c,i,g) wave merge + softmax + coalesced V-gather.
// ---------------------------------------------------------------------------
__global__ __launch_bounds__(256) void k2b2_fin(
    const float* __restrict__ cv, const int* __restrict__ ci,
    const float* __restrict__ V, float* __restrict__ y)
{
    const int w    = (blockIdx.x << 2) + (threadIdx.x >> 6);
    const int lane = threadIdx.x & 63;
    const int c = w >> 14;
    const int i = (w >> 4) & (NT - 1);
    const int g = w & 15;

    float tv[10]; int tidx[10];
    #pragma unroll
    for (int q = 0; q < 10; ++q) { tv[q] = NEG_BIG; tidx[q] = 0; }

    const size_t base = (size_t)w * 40;
    for (int chn = 0; chn < 4; ++chn) {
        const float* cvp = &cv[base + chn * 10];
        const int*   cip = &ci[base + chn * 10];
        for (int q = 9; q >= 0; --q) {
            const float val = cvp[q];
            const int   ix  = cip[q];
            if (val > tv[0]) {
                #pragma unroll
                for (int sl = 0; sl < 10; ++sl) {
                    const bool up   = (sl < 9) ? (val > tv[sl + 1]) : false;
                    const bool here = (val > tv[sl]);
                    const float ntv = up ? tv[sl + 1] : (here ? val : tv[sl]);
                    const int   nti = up ? tidx[sl + 1] : (here ? ix : tidx[sl]);
                    tv[sl] = ntv; tidx[sl] = nti;
                }
            }
        }
    }
    const float m = tv[9];
    float wgt[10]; float sm = 0.f;
    #pragma unroll
    for (int q = 0; q < 10; ++q) { wgt[q] = __expf(tv[q] - m); sm += wgt[q]; }
    const float inv = 1.f / sm;
    float o = 0.f;
    #pragma unroll
    for (int q = 0; q < 10; ++q)
        o += (wgt[q] * inv) * V[((size_t)(c * NT + tidx[q])) * DD + g * 64 + lane];
    y[((size_t)i * CD + c) * DD + g * 64 + lane] = o;
}

extern "C" void kernel_launch(void* const* d_in, const int* in_sizes, int n_in,
                              void* d_out, int out_size, void* d_ws, size_t ws_size,
                              hipStream_t stream) {
    (void)in_sizes; (void)n_in; (void)out_size; (void)ws_size;
    const float* f_a = (const float*)d_in[0];
    const float* pe  = (const float*)d_in[1];
    const float* iou = (const float*)d_in[2];
    const float* WGw = (const float*)d_in[3];
    const float* WGb = (const float*)d_in[4];
    const float* WKw = (const float*)d_in[5];
    const float* WKb = (const float*)d_in[6];
    const float* WQw = (const float*)d_in[7];
    const float* WQb = (const float*)d_in[8];
    const float* Cw  = (const float*)d_in[9];
    const float* Cb  = (const float*)d_in[10];
    float* yout = (float*)d_out;

    float* ws  = (float*)d_ws;
    float* V   = ws + (2u << 21);
    float* aff = ws + (3u << 21);
    float* cv  = ws;
    int*   ci  = (int*)(ws + (1u << 21));
    unsigned short* sp = (unsigned short*)(ws + (3u << 21) + (1u << 25));
    const size_t FN = (size_t)CD * NT * DD;   // 2M
    const size_t WN = (size_t)DD * DD;        // 1M
    unsigned short* Fh  = sp;
    unsigned short* Fm  = Fh + FN;
    unsigned short* Fl  = Fm + FN;
    unsigned short* WQh = Fl + FN;
    unsigned short* WQm = WQh + WN;
    unsigned short* WQl = WQm + WN;
    unsigned short* WKh = WQl + WN;
    unsigned short* WKm = WKh + WN;
    unsigned short* WKl = WKm + WN;
    unsigned short* WCh = WKl + WN;
    unsigned short* WCm = WCh + WN;
    unsigned short* WCl = WCm + WN;
    unsigned short* QSh = WCl + WN;
    unsigned short* QSm = QSh + FN;
    unsigned short* QSl = QSm + FN;
    unsigned short* KSh = QSl + FN;
    unsigned short* KSm = KSh + FN;
    unsigned short* KSl = KSm + FN;

    k0_split<<<dim3(512, 4), 256, 0, stream>>>(f_a, WQw, WKw, Cw,
        Fh, Fm, Fl, WQh, WQm, WQl, WKh, WKm, WKl, WCh, WCm, WCl);
    k1_mfma<<<dim3(16, 16, 3), 256, 0, stream>>>(
        Fh, Fm, Fl, WQh, WQm, WQl, WKh, WKm, WKl, WCh, WCm, WCl,
        WQb, WKb, Cb, V, QSh, QSm, QSl, KSh, KSm, KSl);
    k2a_mfma<<<dim3(16, 16, 32), 256, 0, stream>>>(QSh, QSm, QSl, KSh, KSm, KSl, aff);
    k3_scan<<<dim3(4, 256, 2), 256, 0, stream>>>(pe, iou, WGw, WGb, aff, cv, ci);
    k2b2_fin<<<8192, 256, 0, stream>>>(cv, ci, V, yout);
}

// Round 15
// 414.246 us; speedup vs baseline: 1.0584x; 1.0299x over previous
//
#include <hip/hip_runtime.h>
#include <math.h>

#define NT 1024
#define CD 2
#define DD 1024
#define GG 16
#define LOG1E6 -13.8155105579642740f
#define NEG_BIG -1e30f

typedef short bf16x8 __attribute__((ext_vector_type(8)));
typedef float f32x4  __attribute__((ext_vector_type(4)));

__device__ __forceinline__ unsigned short bf16_rne(float x) {
    unsigned int u = __float_as_uint(x);
    unsigned int r = (u + 0x7fffu + ((u >> 16) & 1u)) >> 16;
    return (unsigned short)r;
}

__device__ __forceinline__ void split3_8(const float* v, bf16x8& h, bf16x8& m, bf16x8& l) {
    #pragma unroll
    for (int e = 0; e < 8; ++e) {
        const float x = v[e];
        const unsigned short hb = bf16_rne(x);
        const float hf = __uint_as_float((unsigned int)hb << 16);
        const float r1 = x - hf;
        const unsigned short mb = bf16_rne(r1);
        const float mf = __uint_as_float((unsigned int)mb << 16);
        const float r2 = r1 - mf;
        const unsigned short lb = bf16_rne(r2);
        h[e] = (short)hb; m[e] = (short)mb; l[e] = (short)lb;
    }
}

// ---------------------------------------------------------------------------
// K0: pre-split fa / Wq / Wk / Wc into exact 3-way bf16 (h+m+l) arrays.
// ---------------------------------------------------------------------------
__global__ __launch_bounds__(256) void k0_split(
    const float* __restrict__ fa, const float* __restrict__ Wq,
    const float* __restrict__ Wk, const float* __restrict__ Wc,
    unsigned short* __restrict__ Fh, unsigned short* __restrict__ Fm, unsigned short* __restrict__ Fl,
    unsigned short* __restrict__ WQh, unsigned short* __restrict__ WQm, unsigned short* __restrict__ WQl,
    unsigned short* __restrict__ WKh, unsigned short* __restrict__ WKm, unsigned short* __restrict__ WKl,
    unsigned short* __restrict__ WCh, unsigned short* __restrict__ WCm, unsigned short* __restrict__ WCl)
{
    const int reg = blockIdx.y;
    const float* src = (reg == 0) ? fa : (reg == 1) ? Wq : (reg == 2) ? Wk : Wc;
    unsigned short* dh = (reg == 0) ? Fh : (reg == 1) ? WQh : (reg == 2) ? WKh : WCh;
    unsigned short* dm = (reg == 0) ? Fm : (reg == 1) ? WQm : (reg == 2) ? WKm : WCm;
    unsigned short* dl = (reg == 0) ? Fl : (reg == 1) ? WQl : (reg == 2) ? WKl : WCl;
    const int nv = (reg == 0) ? (1 << 19) : (1 << 18);   // float4 count

    for (int v = blockIdx.x * 256 + threadIdx.x; v < nv; v += gridDim.x * 256) {
        float4 x4 = *(const float4*)&src[(size_t)v * 4];
        float xv[4] = {x4.x, x4.y, x4.z, x4.w};
        ushort4 h4, m4, l4;
        unsigned short hv[4], mv[4], lv[4];
        #pragma unroll
        for (int q = 0; q < 4; ++q) {
            const float x = xv[q];
            const unsigned short hb = bf16_rne(x);
            const float hf = __uint_as_float((unsigned int)hb << 16);
            const float r1 = x - hf;
            const unsigned short mb = bf16_rne(r1);
            const float mf = __uint_as_float((unsigned int)mb << 16);
            const unsigned short lb = bf16_rne(r1 - mf);
            hv[q] = hb; mv[q] = mb; lv[q] = lb;
        }
        h4.x = hv[0]; h4.y = hv[1]; h4.z = hv[2]; h4.w = hv[3];
        m4.x = mv[0]; m4.y = mv[1]; m4.z = mv[2]; m4.w = mv[3];
        l4.x = lv[0]; l4.y = lv[1]; l4.z = lv[2]; l4.w = lv[3];
        *(ushort4*)&dh[(size_t)v * 4] = h4;
        *(ushort4*)&dm[(size_t)v * 4] = m4;
        *(ushort4*)&dl[(size_t)v * 4] = l4;
    }
}

// ---------------------------------------------------------------------------
// K1 v3 (R11/R12-validated): 6-term MFMA GEMM.  z==2 -> fp32 V out;
// z in {0,1} -> 3-way-split Q/K outputs for k2a_mfma.
// ---------------------------------------------------------------------------
__global__ __launch_bounds__(256) void k1_mfma(
    const unsigned short* __restrict__ Fh, const unsigned short* __restrict__ Fm,
    const unsigned short* __restrict__ Fl,
    const unsigned short* __restrict__ WQh, const unsigned short* __restrict__ WQm,
    const unsigned short* __restrict__ WQl,
    const unsigned short* __restrict__ WKh, const unsigned short* __restrict__ WKm,
    const unsigned short* __restrict__ WKl,
    const unsigned short* __restrict__ WCh, const unsigned short* __restrict__ WCm,
    const unsigned short* __restrict__ WCl,
    const float* __restrict__ bq, const float* __restrict__ bk, const float* __restrict__ bc,
    float* __restrict__ Vo,
    unsigned short* __restrict__ QSh, unsigned short* __restrict__ QSm, unsigned short* __restrict__ QSl,
    unsigned short* __restrict__ KSh, unsigned short* __restrict__ KSm, unsigned short* __restrict__ KSl)
{
    const int et = blockIdx.x, rt = blockIdx.y, z = blockIdx.z;
    const unsigned short* Wh = (z == 0) ? WQh : (z == 1) ? WKh : WCh;
    const unsigned short* Wm = (z == 0) ? WQm : (z == 1) ? WKm : WCm;
    const unsigned short* Wl = (z == 0) ? WQl : (z == 1) ? WKl : WCl;
    const float* bb = (z == 0) ? bq : (z == 1) ? bk : bc;
    unsigned short* Sh = (z == 0) ? QSh : KSh;
    unsigned short* Sm = (z == 0) ? QSm : KSm;
    unsigned short* Sl = (z == 0) ? QSl : KSl;

    const int c  = rt >> 3;
    const int n0 = (rt & 7) * 128;
    const int r0 = rt * 128;
    const int e0 = et * 64;

    __shared__ unsigned short Ah[128][36], Am[128][36], Al[128][36];
    __shared__ unsigned short Bh[64][36],  Bm[64][36],  Bl[64][36];

    const int t    = threadIdx.x;
    const int wave = t >> 6, lane = t & 63;
    const int wr   = wave >> 1, wc = wave & 1;
    const int lrow = lane & 15, lk = lane >> 4;

    f32x4 acc[4][2];
    #pragma unroll
    for (int m = 0; m < 4; ++m)
        #pragma unroll
        for (int n = 0; n < 2; ++n) acc[m][n] = (f32x4){0.f, 0.f, 0.f, 0.f};

    for (int kt = 0; kt < 32; ++kt) {
        const int kb = kt * 32;
        #pragma unroll
        for (int p = 0; p < 2; ++p) {
            const int task = t + p * 256;
            const int row = task >> 2, seg = task & 3;
            const size_t gs = ((size_t)((n0 + row) * CD + c)) * DD + kb + seg * 8;
            *(uint4*)&Ah[row][seg * 8] = *(const uint4*)&Fh[gs];
            *(uint4*)&Am[row][seg * 8] = *(const uint4*)&Fm[gs];
            *(uint4*)&Al[row][seg * 8] = *(const uint4*)&Fl[gs];
        }
        {
            const int row = t >> 2, seg = t & 3;
            const size_t gs = ((size_t)(e0 + row)) * DD + kb + seg * 8;
            *(uint4*)&Bh[row][seg * 8] = *(const uint4*)&Wh[gs];
            *(uint4*)&Bm[row][seg * 8] = *(const uint4*)&Wm[gs];
            *(uint4*)&Bl[row][seg * 8] = *(const uint4*)&Wl[gs];
        }
        __syncthreads();
        {
            bf16x8 ah[4], am[4], al[4], bh[2], bm[2], bl[2];
            #pragma unroll
            for (int m = 0; m < 4; ++m) {
                const int row = wr * 64 + m * 16 + lrow;
                ah[m] = *(const bf16x8*)&Ah[row][lk * 8];
                am[m] = *(const bf16x8*)&Am[row][lk * 8];
                al[m] = *(const bf16x8*)&Al[row][lk * 8];
            }
            #pragma unroll
            for (int n = 0; n < 2; ++n) {
                const int row = wc * 32 + n * 16 + lrow;
                bh[n] = *(const bf16x8*)&Bh[row][lk * 8];
                bm[n] = *(const bf16x8*)&Bm[row][lk * 8];
                bl[n] = *(const bf16x8*)&Bl[row][lk * 8];
            }
            #pragma unroll
            for (int m = 0; m < 4; ++m)
                #pragma unroll
                for (int n = 0; n < 2; ++n) {
                    acc[m][n] = __builtin_amdgcn_mfma_f32_16x16x32_bf16(al[m], bh[n], acc[m][n], 0, 0, 0);
                    acc[m][n] = __builtin_amdgcn_mfma_f32_16x16x32_bf16(ah[m], bl[n], acc[m][n], 0, 0, 0);
                    acc[m][n] = __builtin_amdgcn_mfma_f32_16x16x32_bf16(am[m], bm[n], acc[m][n], 0, 0, 0);
                    acc[m][n] = __builtin_amdgcn_mfma_f32_16x16x32_bf16(am[m], bh[n], acc[m][n], 0, 0, 0);
                    acc[m][n] = __builtin_amdgcn_mfma_f32_16x16x32_bf16(ah[m], bm[n], acc[m][n], 0, 0, 0);
                    acc[m][n] = __builtin_amdgcn_mfma_f32_16x16x32_bf16(ah[m], bh[n], acc[m][n], 0, 0, 0);
                }
        }
        __syncthreads();
    }
    #pragma unroll
    for (int n = 0; n < 2; ++n) {
        const int e = e0 + wc * 32 + n * 16 + lrow;
        const float bias = bb[e];
        #pragma unroll
        for (int m = 0; m < 4; ++m) {
            const int r = r0 + wr * 64 + m * 16 + lk * 4;
            #pragma unroll
            for (int q = 0; q < 4; ++q) {
                const float val = acc[m][n][q] + bias;
                const size_t idx = ((size_t)(r + q)) * DD + e;
                if (z == 2) {
                    Vo[idx] = val;
                } else {
                    const unsigned short hb = bf16_rne(val);
                    const float hf = __uint_as_float((unsigned int)hb << 16);
                    const float r1 = val - hf;
                    const unsigned short mb = bf16_rne(r1);
                    const float mf = __uint_as_float((unsigned int)mb << 16);
                    const unsigned short lb = bf16_rne(r1 - mf);
                    Sh[idx] = hb; Sm[idx] = mb; Sl[idx] = lb;
                }
            }
        }
    }
}

// ---------------------------------------------------------------------------
// K2a v3 (R12-validated): aff = Q.K^T/8 on the matrix pipe.
// ---------------------------------------------------------------------------
__global__ __launch_bounds__(256) void k2a_mfma(
    const unsigned short* __restrict__ QSh, const unsigned short* __restrict__ QSm,
    const unsigned short* __restrict__ QSl,
    const unsigned short* __restrict__ KSh, const unsigned short* __restrict__ KSm,
    const unsigned short* __restrict__ KSl,
    float* __restrict__ aff)
{
    const int jt = blockIdx.x, it = blockIdx.y, cg = blockIdx.z;
    const int c = cg >> 4, g = cg & 15;
    const int i0 = it * 64, j0 = jt * 64;

    __shared__ unsigned short Qh[64][36], Qm[64][36], Ql[64][36];
    __shared__ unsigned short Kh[64][36], Km[64][36], Kl[64][36];

    const int t    = threadIdx.x;
    const int wave = t >> 6, lane = t & 63;
    const int wr   = wave >> 1, wc = wave & 1;
    const int lrow = lane & 15, lk = lane >> 4;

    f32x4 acc[2][2];
    #pragma unroll
    for (int m = 0; m < 2; ++m)
        #pragma unroll
        for (int n = 0; n < 2; ++n) acc[m][n] = (f32x4){0.f, 0.f, 0.f, 0.f};

    for (int kt = 0; kt < 2; ++kt) {
        const int kb = g * 64 + kt * 32;
        {
            const int row = t >> 2, seg = t & 3;
            const size_t qs = ((size_t)(c * NT + i0 + row)) * DD + kb + seg * 8;
            *(uint4*)&Qh[row][seg * 8] = *(const uint4*)&QSh[qs];
            *(uint4*)&Qm[row][seg * 8] = *(const uint4*)&QSm[qs];
            *(uint4*)&Ql[row][seg * 8] = *(const uint4*)&QSl[qs];
            const size_t ks = ((size_t)(c * NT + j0 + row)) * DD + kb + seg * 8;
            *(uint4*)&Kh[row][seg * 8] = *(const uint4*)&KSh[ks];
            *(uint4*)&Km[row][seg * 8] = *(const uint4*)&KSm[ks];
            *(uint4*)&Kl[row][seg * 8] = *(const uint4*)&KSl[ks];
        }
        __syncthreads();
        {
            bf16x8 qh[2], qm[2], ql[2], kh[2], km[2], kl[2];
            #pragma unroll
            for (int m = 0; m < 2; ++m) {
                const int row = wr * 32 + m * 16 + lrow;
                qh[m] = *(const bf16x8*)&Qh[row][lk * 8];
                qm[m] = *(const bf16x8*)&Qm[row][lk * 8];
                ql[m] = *(const bf16x8*)&Ql[row][lk * 8];
            }
            #pragma unroll
            for (int n = 0; n < 2; ++n) {
                const int row = wc * 32 + n * 16 + lrow;
                kh[n] = *(const bf16x8*)&Kh[row][lk * 8];
                km[n] = *(const bf16x8*)&Km[row][lk * 8];
                kl[n] = *(const bf16x8*)&Kl[row][lk * 8];
            }
            #pragma unroll
            for (int m = 0; m < 2; ++m)
                #pragma unroll
                for (int n = 0; n < 2; ++n) {
                    acc[m][n] = __builtin_amdgcn_mfma_f32_16x16x32_bf16(ql[m], kh[n], acc[m][n], 0, 0, 0);
                    acc[m][n] = __builtin_amdgcn_mfma_f32_16x16x32_bf16(qh[m], kl[n], acc[m][n], 0, 0, 0);
                    acc[m][n] = __builtin_amdgcn_mfma_f32_16x16x32_bf16(qm[m], km[n], acc[m][n], 0, 0, 0);
                    acc[m][n] = __builtin_amdgcn_mfma_f32_16x16x32_bf16(qm[m], kh[n], acc[m][n], 0, 0, 0);
                    acc[m][n] = __builtin_amdgcn_mfma_f32_16x16x32_bf16(qh[m], km[n], acc[m][n], 0, 0, 0);
                    acc[m][n] = __builtin_amdgcn_mfma_f32_16x16x32_bf16(qh[m], kh[n], acc[m][n], 0, 0, 0);
                }
        }
        __syncthreads();
    }
    #pragma unroll
    for (int m = 0; m < 2; ++m) {
        const int i = i0 + wr * 32 + m * 16 + lk * 4;
        #pragma unroll
        for (int n = 0; n < 2; ++n) {
            const int j = j0 + wc * 32 + n * 16 + lrow;
            #pragma unroll
            for (int q = 0; q < 4; ++q)
                aff[((size_t)cg * NT + i + q) * NT + j] = acc[m][n][q] * 0.125f;
        }
    }
}

// ---------------------------------------------------------------------------
// K3 v7 = R12-v4 (best measured k3, 2-phase LDS) + aff REGISTER PREFETCH:
//   phase-S's aff loads are issued at phase-G START (same subtile) into 4
//   float4 registers, so they complete under phase-G's MFMA work + barrier
//   instead of exposing HBM/L3 latency to all waves after the barrier
//   (Guideline-15 issue-early/consume-late; +17% on the attn ladder).
//   All arithmetic and scan order identical to R12 -> absmax unchanged.
// ---------------------------------------------------------------------------
__global__ __launch_bounds__(256, 4) void k3_scan(
    const float* __restrict__ pe, const float* __restrict__ iou,
    const float* __restrict__ WGw, const float* __restrict__ WGb,
    const float* __restrict__ aff,
    float* __restrict__ cv, int* __restrict__ ci)
{
    const int ch = blockIdx.x;   // 0..3
    const int it = blockIdx.y;   // 0..127
    const int c  = blockIdx.z;
    const int i0 = it * 8;

    __shared__ float wgl[8][16][33];
    __shared__ float ios[8][33];

    const int t = threadIdx.x;
    const int wave = t >> 6, lane = t & 63;
    const int lg = lane & 15, lk = lane >> 4;
    const int p_i = t >> 5, jq = t & 31;
    const int s_i = t >> 5, s_g = (t >> 1) & 15, s_h = t & 1;

    bf16x8 bh[2], bm[2], bl[2];
    #pragma unroll
    for (int kp = 0; kp < 2; ++kp) {
        float w8[8];
        float4 w0 = *(const float4*)&WGw[lg * 64 + kp * 32 + lk * 8];
        float4 w1 = *(const float4*)&WGw[lg * 64 + kp * 32 + lk * 8 + 4];
        w8[0]=w0.x; w8[1]=w0.y; w8[2]=w0.z; w8[3]=w0.w;
        w8[4]=w1.x; w8[5]=w1.y; w8[6]=w1.z; w8[7]=w1.w;
        split3_8(w8, bh[kp], bm[kp], bl[kp]);
    }
    const float bias = WGb[lg];

    float tv[10]; int tidx[10];
    #pragma unroll
    for (int q = 0; q < 10; ++q) { tv[q] = NEG_BIG; tidx[q] = 0; }

    const float* afrow = &aff[(((size_t)(c * GG + s_g)) * NT + (i0 + s_i)) * NT];

    for (int s = 0; s < 8; ++s) {
        const int j0 = ch * 256 + s * 32;
        // ---- prefetch this subtile's aff (phase-S data) into registers ----
        float4 af0 = *(const float4*)&afrow[j0 + s_h * 16];
        float4 af1 = *(const float4*)&afrow[j0 + s_h * 16 + 4];
        float4 af2 = *(const float4*)&afrow[j0 + s_h * 16 + 8];
        float4 af3 = *(const float4*)&afrow[j0 + s_h * 16 + 12];
        // ---- ios staging ----
        {
            const float ia = iou[((size_t)c * NT + (i0 + p_i)) * NT + j0 + jq];
            ios[p_i][jq] = (ia >= 1e-6f) ? 0.f : LOG1E6;
        }
        // ---- phase G: 4 row-tiles per wave, 12 MFMAs each ----
        #pragma unroll 1
        for (int rtt = 0; rtt < 4; ++rtt) {
            const int rt = wave * 4 + rtt;
            const int ib = rt >> 1;
            const int jb = (rt & 1) * 16;
            const float* pr = &pe[(((size_t)c * NT + (i0 + ib)) * NT + (j0 + jb + lg)) * 64];
            f32x4 acc = {0.f, 0.f, 0.f, 0.f};
            #pragma unroll
            for (int kp = 0; kp < 2; ++kp) {
                float a8[8];
                float4 v0 = *(const float4*)&pr[kp * 32 + lk * 8];
                float4 v1 = *(const float4*)&pr[kp * 32 + lk * 8 + 4];
                a8[0]=v0.x; a8[1]=v0.y; a8[2]=v0.z; a8[3]=v0.w;
                a8[4]=v1.x; a8[5]=v1.y; a8[6]=v1.z; a8[7]=v1.w;
                bf16x8 ah, am, al;
                split3_8(a8, ah, am, al);
                acc = __builtin_amdgcn_mfma_f32_16x16x32_bf16(al, bh[kp], acc, 0, 0, 0);
                acc = __builtin_amdgcn_mfma_f32_16x16x32_bf16(ah, bl[kp], acc, 0, 0, 0);
                acc = __builtin_amdgcn_mfma_f32_16x16x32_bf16(am, bm[kp], acc, 0, 0, 0);
                acc = __builtin_amdgcn_mfma_f32_16x16x32_bf16(am, bh[kp], acc, 0, 0, 0);
                acc = __builtin_amdgcn_mfma_f32_16x16x32_bf16(ah, bm[kp], acc, 0, 0, 0);
                acc = __builtin_amdgcn_mfma_f32_16x16x32_bf16(ah, bh[kp], acc, 0, 0, 0);
            }
            #pragma unroll
            for (int q = 0; q < 4; ++q) {
                const float v = acc[q] + bias;
                wgl[ib][lg][jb + lk * 4 + q] = (v > 1e-6f) ? __logf(v) : LOG1E6;
            }
        }
        __syncthreads();
        // ---- phase S: 16 j per thread, aff from registers ----
        {
            const float* wl = &wgl[s_i][s_g][s_h * 16];
            const float* il = &ios[s_i][s_h * 16];
            float av[16] = {af0.x, af0.y, af0.z, af0.w,
                            af1.x, af1.y, af1.z, af1.w,
                            af2.x, af2.y, af2.z, af2.w,
                            af3.x, af3.y, af3.z, af3.w};
            #pragma unroll
            for (int j4 = 0; j4 < 16; j4 += 4) {
                #pragma unroll
                for (int q = 0; q < 4; ++q) {
                    const float val = wl[j4 + q] + av[j4 + q] + il[j4 + q];
                    if (val > tv[0]) {
                        const int ix = j0 + s_h * 16 + j4 + q;
                        #pragma unroll
                        for (int sl = 0; sl < 10; ++sl) {
                            const bool up   = (sl < 9) ? (val > tv[sl + 1]) : false;
                            const bool here = (val > tv[sl]);
                            const float ntv = up ? tv[sl + 1] : (here ? val : tv[sl]);
                            const int   nti = up ? tidx[sl + 1] : (here ? ix : tidx[sl]);
                            tv[sl] = ntv; tidx[sl] = nti;
                        }
                    }
                }
            }
        }
        __syncthreads();
    }

    float* mv = &wgl[0][0][0];
    int*   mi = (int*)(mv + 1280);
    const int pair = t >> 1;
    if (s_h == 1) {
        #pragma unroll
        for (int q = 0; q < 10; ++q) { mv[pair * 10 + q] = tv[q]; mi[pair * 10 + q] = tidx[q]; }
    }
    __syncthreads();
    if (s_h == 0) {
        for (int q = 9; q >= 0; --q) {
            const float val = mv[pair * 10 + q];
            const int   ix  = mi[pair * 10 + q];
            if (val > tv[0]) {
                #pragma unroll
                for (int sl = 0; sl < 10; ++sl) {
                    const bool up   = (sl < 9) ? (val > tv[sl + 1]) : false;
                    const bool here = (val > tv[sl]);
                    const float ntv = up ? tv[sl + 1] : (here ? val : tv[sl]);
                    const int   nti = up ? tidx[sl + 1] : (here ? ix : tidx[sl]);
                    tv[sl] = ntv; tidx[sl] = nti;
                }
            }
        }
        const size_t base = ((((size_t)c * NT + (i0 + s_i)) * GG + s_g) * 4 + ch) * 10;
        #pragma unroll
        for (int q = 0; q < 10; ++q) { cv[base + q] = tv[q]; ci[base + q] = tidx[q]; }
    }
}

// ---------------------------------------------------------------------------
// K2b2 (unchanged): per-(c,i,g) wave merge + softmax + coalesced V-gather.
// ---------------------------------------------------------------------------
__global__ __launch_bounds__(256) void k2b2_fin(
    const float* __restrict__ cv, const int* __restrict__ ci,
    const float* __restrict__ V, float* __restrict__ y)
{
    const int w    = (blockIdx.x << 2) + (threadIdx.x >> 6);
    const int lane = threadIdx.x & 63;
    const int c = w >> 14;
    const int i = (w >> 4) & (NT - 1);
    const int g = w & 15;

    float tv[10]; int tidx[10];
    #pragma unroll
    for (int q = 0; q < 10; ++q) { tv[q] = NEG_BIG; tidx[q] = 0; }

    const size_t base = (size_t)w * 40;
    for (int chn = 0; chn < 4; ++chn) {
        const float* cvp = &cv[base + chn * 10];
        const int*   cip = &ci[base + chn * 10];
        for (int q = 9; q >= 0; --q) {
            const float val = cvp[q];
            const int   ix  = cip[q];
            if (val > tv[0]) {
                #pragma unroll
                for (int sl = 0; sl < 10; ++sl) {
                    const bool up   = (sl < 9) ? (val > tv[sl + 1]) : false;
                    const bool here = (val > tv[sl]);
                    const float ntv = up ? tv[sl + 1] : (here ? val : tv[sl]);
                    const int   nti = up ? tidx[sl + 1] : (here ? ix : tidx[sl]);
                    tv[sl] = ntv; tidx[sl] = nti;
                }
            }
        }
    }
    const float m = tv[9];
    float wgt[10]; float sm = 0.f;
    #pragma unroll
    for (int q = 0; q < 10; ++q) { wgt[q] = __expf(tv[q] - m); sm += wgt[q]; }
    const float inv = 1.f / sm;
    float o = 0.f;
    #pragma unroll
    for (int q = 0; q < 10; ++q)
        o += (wgt[q] * inv) * V[((size_t)(c * NT + tidx[q])) * DD + g * 64 + lane];
    y[((size_t)i * CD + c) * DD + g * 64 + lane] = o;
}

extern "C" void kernel_launch(void* const* d_in, const int* in_sizes, int n_in,
                              void* d_out, int out_size, void* d_ws, size_t ws_size,
                              hipStream_t stream) {
    (void)in_sizes; (void)n_in; (void)out_size; (void)ws_size;
    const float* f_a = (const float*)d_in[0];
    const float* pe  = (const float*)d_in[1];
    const float* iou = (const float*)d_in[2];
    const float* WGw = (const float*)d_in[3];
    const float* WGb = (const float*)d_in[4];
    const float* WKw = (const float*)d_in[5];
    const float* WKb = (const float*)d_in[6];
    const float* WQw = (const float*)d_in[7];
    const float* WQb = (const float*)d_in[8];
    const float* Cw  = (const float*)d_in[9];
    const float* Cb  = (const float*)d_in[10];
    float* yout = (float*)d_out;

    float* ws  = (float*)d_ws;
    float* V   = ws + (2u << 21);
    float* aff = ws + (3u << 21);
    float* cv  = ws;
    int*   ci  = (int*)(ws + (1u << 21));
    unsigned short* sp = (unsigned short*)(ws + (3u << 21) + (1u << 25));
    const size_t FN = (size_t)CD * NT * DD;   // 2M
    const size_t WN = (size_t)DD * DD;        // 1M
    unsigned short* Fh  = sp;
    unsigned short* Fm  = Fh + FN;
    unsigned short* Fl  = Fm + FN;
    unsigned short* WQh = Fl + FN;
    unsigned short* WQm = WQh + WN;
    unsigned short* WQl = WQm + WN;
    unsigned short* WKh = WQl + WN;
    unsigned short* WKm = WKh + WN;
    unsigned short* WKl = WKm + WN;
    unsigned short* WCh = WKl + WN;
    unsigned short* WCm = WCh + WN;
    unsigned short* WCl = WCm + WN;
    unsigned short* QSh = WCl + WN;
    unsigned short* QSm = QSh + FN;
    unsigned short* QSl = QSm + FN;
    unsigned short* KSh = QSl + FN;
    unsigned short* KSm = KSh + FN;
    unsigned short* KSl = KSm + FN;

    k0_split<<<dim3(512, 4), 256, 0, stream>>>(f_a, WQw, WKw, Cw,
        Fh, Fm, Fl, WQh, WQm, WQl, WKh, WKm, WKl, WCh, WCm, WCl);
    k1_mfma<<<dim3(16, 16, 3), 256, 0, stream>>>(
        Fh, Fm, Fl, WQh, WQm, WQl, WKh, WKm, WKl, WCh, WCm, WCl,
        WQb, WKb, Cb, V, QSh, QSm, QSl, KSh, KSm, KSl);
    k2a_mfma<<<dim3(16, 16, 32), 256, 0, stream>>>(QSh, QSm, QSl, KSh, KSm, KSl, aff);
    k3_scan<<<dim3(4, 128, 2), 256, 0, stream>>>(pe, iou, WGw, WGb, aff, cv, ci);
    k2b2_fin<<<8192, 256, 0, stream>>>(cv, ci, V, yout);
}

// Round 16
// 411.473 us; speedup vs baseline: 1.0655x; 1.0067x over previous
//
#include <hip/hip_runtime.h>
#include <math.h>

#define NT 1024
#define CD 2
#define DD 1024
#define GG 16
#define LOG1E6 -13.8155105579642740f
#define NEG_BIG -1e30f

typedef short bf16x8 __attribute__((ext_vector_type(8)));
typedef float f32x4  __attribute__((ext_vector_type(4)));

__device__ __forceinline__ unsigned short bf16_rne(float x) {
    unsigned int u = __float_as_uint(x);
    unsigned int r = (u + 0x7fffu + ((u >> 16) & 1u)) >> 16;
    return (unsigned short)r;
}

__device__ __forceinline__ void split3_8(const float* v, bf16x8& h, bf16x8& m, bf16x8& l) {
    #pragma unroll
    for (int e = 0; e < 8; ++e) {
        const float x = v[e];
        const unsigned short hb = bf16_rne(x);
        const float hf = __uint_as_float((unsigned int)hb << 16);
        const float r1 = x - hf;
        const unsigned short mb = bf16_rne(r1);
        const float mf = __uint_as_float((unsigned int)mb << 16);
        const float r2 = r1 - mf;
        const unsigned short lb = bf16_rne(r2);
        h[e] = (short)hb; m[e] = (short)mb; l[e] = (short)lb;
    }
}

// ---------------------------------------------------------------------------
// K0: pre-split fa / Wq / Wk / Wc into exact 3-way bf16 (h+m+l) arrays.
// ---------------------------------------------------------------------------
__global__ __launch_bounds__(256) void k0_split(
    const float* __restrict__ fa, const float* __restrict__ Wq,
    const float* __restrict__ Wk, const float* __restrict__ Wc,
    unsigned short* __restrict__ Fh, unsigned short* __restrict__ Fm, unsigned short* __restrict__ Fl,
    unsigned short* __restrict__ WQh, unsigned short* __restrict__ WQm, unsigned short* __restrict__ WQl,
    unsigned short* __restrict__ WKh, unsigned short* __restrict__ WKm, unsigned short* __restrict__ WKl,
    unsigned short* __restrict__ WCh, unsigned short* __restrict__ WCm, unsigned short* __restrict__ WCl)
{
    const int reg = blockIdx.y;
    const float* src = (reg == 0) ? fa : (reg == 1) ? Wq : (reg == 2) ? Wk : Wc;
    unsigned short* dh = (reg == 0) ? Fh : (reg == 1) ? WQh : (reg == 2) ? WKh : WCh;
    unsigned short* dm = (reg == 0) ? Fm : (reg == 1) ? WQm : (reg == 2) ? WKm : WCm;
    unsigned short* dl = (reg == 0) ? Fl : (reg == 1) ? WQl : (reg == 2) ? WKl : WCl;
    const int nv = (reg == 0) ? (1 << 19) : (1 << 18);   // float4 count

    for (int v = blockIdx.x * 256 + threadIdx.x; v < nv; v += gridDim.x * 256) {
        float4 x4 = *(const float4*)&src[(size_t)v * 4];
        float xv[4] = {x4.x, x4.y, x4.z, x4.w};
        ushort4 h4, m4, l4;
        unsigned short hv[4], mv[4], lv[4];
        #pragma unroll
        for (int q = 0; q < 4; ++q) {
            const float x = xv[q];
            const unsigned short hb = bf16_rne(x);
            const float hf = __uint_as_float((unsigned int)hb << 16);
            const float r1 = x - hf;
            const unsigned short mb = bf16_rne(r1);
            const float mf = __uint_as_float((unsigned int)mb << 16);
            const unsigned short lb = bf16_rne(r1 - mf);
            hv[q] = hb; mv[q] = mb; lv[q] = lb;
        }
        h4.x = hv[0]; h4.y = hv[1]; h4.z = hv[2]; h4.w = hv[3];
        m4.x = mv[0]; m4.y = mv[1]; m4.z = mv[2]; m4.w = mv[3];
        l4.x = lv[0]; l4.y = lv[1]; l4.z = lv[2]; l4.w = lv[3];
        *(ushort4*)&dh[(size_t)v * 4] = h4;
        *(ushort4*)&dm[(size_t)v * 4] = m4;
        *(ushort4*)&dl[(size_t)v * 4] = l4;
    }
}

// ---------------------------------------------------------------------------
// K1 v3 (R11/R12-validated): 6-term MFMA GEMM.  z==2 -> fp32 V out;
// z in {0,1} -> 3-way-split Q/K outputs for k2a_mfma.
// ---------------------------------------------------------------------------
__global__ __launch_bounds__(256) void k1_mfma(
    const unsigned short* __restrict__ Fh, const unsigned short* __restrict__ Fm,
    const unsigned short* __restrict__ Fl,
    const unsigned short* __restrict__ WQh, const unsigned short* __restrict__ WQm,
    const unsigned short* __restrict__ WQl,
    const unsigned short* __restrict__ WKh, const unsigned short* __restrict__ WKm,
    const unsigned short* __restrict__ WKl,
    const unsigned short* __restrict__ WCh, const unsigned short* __restrict__ WCm,
    const unsigned short* __restrict__ WCl,
    const float* __restrict__ bq, const float* __restrict__ bk, const float* __restrict__ bc,
    float* __restrict__ Vo,
    unsigned short* __restrict__ QSh, unsigned short* __restrict__ QSm, unsigned short* __restrict__ QSl,
    unsigned short* __restrict__ KSh, unsigned short* __restrict__ KSm, unsigned short* __restrict__ KSl)
{
    const int et = blockIdx.x, rt = blockIdx.y, z = blockIdx.z;
    const unsigned short* Wh = (z == 0) ? WQh : (z == 1) ? WKh : WCh;
    const unsigned short* Wm = (z == 0) ? WQm : (z == 1) ? WKm : WCm;
    const unsigned short* Wl = (z == 0) ? WQl : (z == 1) ? WKl : WCl;
    const float* bb = (z == 0) ? bq : (z == 1) ? bk : bc;
    unsigned short* Sh = (z == 0) ? QSh : KSh;
    unsigned short* Sm = (z == 0) ? QSm : KSm;
    unsigned short* Sl = (z == 0) ? QSl : KSl;

    const int c  = rt >> 3;
    const int n0 = (rt & 7) * 128;
    const int r0 = rt * 128;
    const int e0 = et * 64;

    __shared__ unsigned short Ah[128][36], Am[128][36], Al[128][36];
    __shared__ unsigned short Bh[64][36],  Bm[64][36],  Bl[64][36];

    const int t    = threadIdx.x;
    const int wave = t >> 6, lane = t & 63;
    const int wr   = wave >> 1, wc = wave & 1;
    const int lrow = lane & 15, lk = lane >> 4;

    f32x4 acc[4][2];
    #pragma unroll
    for (int m = 0; m < 4; ++m)
        #pragma unroll
        for (int n = 0; n < 2; ++n) acc[m][n] = (f32x4){0.f, 0.f, 0.f, 0.f};

    for (int kt = 0; kt < 32; ++kt) {
        const int kb = kt * 32;
        #pragma unroll
        for (int p = 0; p < 2; ++p) {
            const int task = t + p * 256;
            const int row = task >> 2, seg = task & 3;
            const size_t gs = ((size_t)((n0 + row) * CD + c)) * DD + kb + seg * 8;
            *(uint4*)&Ah[row][seg * 8] = *(const uint4*)&Fh[gs];
            *(uint4*)&Am[row][seg * 8] = *(const uint4*)&Fm[gs];
            *(uint4*)&Al[row][seg * 8] = *(const uint4*)&Fl[gs];
        }
        {
            const int row = t >> 2, seg = t & 3;
            const size_t gs = ((size_t)(e0 + row)) * DD + kb + seg * 8;
            *(uint4*)&Bh[row][seg * 8] = *(const uint4*)&Wh[gs];
            *(uint4*)&Bm[row][seg * 8] = *(const uint4*)&Wm[gs];
            *(uint4*)&Bl[row][seg * 8] = *(const uint4*)&Wl[gs];
        }
        __syncthreads();
        {
            bf16x8 ah[4], am[4], al[4], bh[2], bm[2], bl[2];
            #pragma unroll
            for (int m = 0; m < 4; ++m) {
                const int row = wr * 64 + m * 16 + lrow;
                ah[m] = *(const bf16x8*)&Ah[row][lk * 8];
                am[m] = *(const bf16x8*)&Am[row][lk * 8];
                al[m] = *(const bf16x8*)&Al[row][lk * 8];
            }
            #pragma unroll
            for (int n = 0; n < 2; ++n) {
                const int row = wc * 32 + n * 16 + lrow;
                bh[n] = *(const bf16x8*)&Bh[row][lk * 8];
                bm[n] = *(const bf16x8*)&Bm[row][lk * 8];
                bl[n] = *(const bf16x8*)&Bl[row][lk * 8];
            }
            #pragma unroll
            for (int m = 0; m < 4; ++m)
                #pragma unroll
                for (int n = 0; n < 2; ++n) {
                    acc[m][n] = __builtin_amdgcn_mfma_f32_16x16x32_bf16(al[m], bh[n], acc[m][n], 0, 0, 0);
                    acc[m][n] = __builtin_amdgcn_mfma_f32_16x16x32_bf16(ah[m], bl[n], acc[m][n], 0, 0, 0);
                    acc[m][n] = __builtin_amdgcn_mfma_f32_16x16x32_bf16(am[m], bm[n], acc[m][n], 0, 0, 0);
                    acc[m][n] = __builtin_amdgcn_mfma_f32_16x16x32_bf16(am[m], bh[n], acc[m][n], 0, 0, 0);
                    acc[m][n] = __builtin_amdgcn_mfma_f32_16x16x32_bf16(ah[m], bm[n], acc[m][n], 0, 0, 0);
                    acc[m][n] = __builtin_amdgcn_mfma_f32_16x16x32_bf16(ah[m], bh[n], acc[m][n], 0, 0, 0);
                }
        }
        __syncthreads();
    }
    #pragma unroll
    for (int n = 0; n < 2; ++n) {
        const int e = e0 + wc * 32 + n * 16 + lrow;
        const float bias = bb[e];
        #pragma unroll
        for (int m = 0; m < 4; ++m) {
            const int r = r0 + wr * 64 + m * 16 + lk * 4;
            #pragma unroll
            for (int q = 0; q < 4; ++q) {
                const float val = acc[m][n][q] + bias;
                const size_t idx = ((size_t)(r + q)) * DD + e;
                if (z == 2) {
                    Vo[idx] = val;
                } else {
                    const unsigned short hb = bf16_rne(val);
                    const float hf = __uint_as_float((unsigned int)hb << 16);
                    const float r1 = val - hf;
                    const unsigned short mb = bf16_rne(r1);
                    const float mf = __uint_as_float((unsigned int)mb << 16);
                    const unsigned short lb = bf16_rne(r1 - mf);
                    Sh[idx] = hb; Sm[idx] = mb; Sl[idx] = lb;
                }
            }
        }
    }
}

// ---------------------------------------------------------------------------
// K2a v3 (R12-validated): aff = Q.K^T/8 on the matrix pipe.
// ---------------------------------------------------------------------------
__global__ __launch_bounds__(256) void k2a_mfma(
    const unsigned short* __restrict__ QSh, const unsigned short* __restrict__ QSm,
    const unsigned short* __restrict__ QSl,
    const unsigned short* __restrict__ KSh, const unsigned short* __restrict__ KSm,
    const unsigned short* __restrict__ KSl,
    float* __restrict__ aff)
{
    const int jt = blockIdx.x, it = blockIdx.y, cg = blockIdx.z;
    const int c = cg >> 4, g = cg & 15;
    const int i0 = it * 64, j0 = jt * 64;

    __shared__ unsigned short Qh[64][36], Qm[64][36], Ql[64][36];
    __shared__ unsigned short Kh[64][36], Km[64][36], Kl[64][36];

    const int t    = threadIdx.x;
    const int wave = t >> 6, lane = t & 63;
    const int wr   = wave >> 1, wc = wave & 1;
    const int lrow = lane & 15, lk = lane >> 4;

    f32x4 acc[2][2];
    #pragma unroll
    for (int m = 0; m < 2; ++m)
        #pragma unroll
        for (int n = 0; n < 2; ++n) acc[m][n] = (f32x4){0.f, 0.f, 0.f, 0.f};

    for (int kt = 0; kt < 2; ++kt) {
        const int kb = g * 64 + kt * 32;
        {
            const int row = t >> 2, seg = t & 3;
            const size_t qs = ((size_t)(c * NT + i0 + row)) * DD + kb + seg * 8;
            *(uint4*)&Qh[row][seg * 8] = *(const uint4*)&QSh[qs];
            *(uint4*)&Qm[row][seg * 8] = *(const uint4*)&QSm[qs];
            *(uint4*)&Ql[row][seg * 8] = *(const uint4*)&QSl[qs];
            const size_t ks = ((size_t)(c * NT + j0 + row)) * DD + kb + seg * 8;
            *(uint4*)&Kh[row][seg * 8] = *(const uint4*)&KSh[ks];
            *(uint4*)&Km[row][seg * 8] = *(const uint4*)&KSm[ks];
            *(uint4*)&Kl[row][seg * 8] = *(const uint4*)&KSl[ks];
        }
        __syncthreads();
        {
            bf16x8 qh[2], qm[2], ql[2], kh[2], km[2], kl[2];
            #pragma unroll
            for (int m = 0; m < 2; ++m) {
                const int row = wr * 32 + m * 16 + lrow;
                qh[m] = *(const bf16x8*)&Qh[row][lk * 8];
                qm[m] = *(const bf16x8*)&Qm[row][lk * 8];
                ql[m] = *(const bf16x8*)&Ql[row][lk * 8];
            }
            #pragma unroll
            for (int n = 0; n < 2; ++n) {
                const int row = wc * 32 + n * 16 + lrow;
                kh[n] = *(const bf16x8*)&Kh[row][lk * 8];
                km[n] = *(const bf16x8*)&Km[row][lk * 8];
                kl[n] = *(const bf16x8*)&Kl[row][lk * 8];
            }
            #pragma unroll
            for (int m = 0; m < 2; ++m)
                #pragma unroll
                for (int n = 0; n < 2; ++n) {
                    acc[m][n] = __builtin_amdgcn_mfma_f32_16x16x32_bf16(ql[m], kh[n], acc[m][n], 0, 0, 0);
                    acc[m][n] = __builtin_amdgcn_mfma_f32_16x16x32_bf16(qh[m], kl[n], acc[m][n], 0, 0, 0);
                    acc[m][n] = __builtin_amdgcn_mfma_f32_16x16x32_bf16(qm[m], km[n], acc[m][n], 0, 0, 0);
                    acc[m][n] = __builtin_amdgcn_mfma_f32_16x16x32_bf16(qm[m], kh[n], acc[m][n], 0, 0, 0);
                    acc[m][n] = __builtin_amdgcn_mfma_f32_16x16x32_bf16(qh[m], km[n], acc[m][n], 0, 0, 0);
                    acc[m][n] = __builtin_amdgcn_mfma_f32_16x16x32_bf16(qh[m], kh[n], acc[m][n], 0, 0, 0);
                }
        }
        __syncthreads();
    }
    #pragma unroll
    for (int m = 0; m < 2; ++m) {
        const int i = i0 + wr * 32 + m * 16 + lk * 4;
        #pragma unroll
        for (int n = 0; n < 2; ++n) {
            const int j = j0 + wc * 32 + n * 16 + lrow;
            #pragma unroll
            for (int q = 0; q < 4; ++q)
                aff[((size_t)cg * NT + i + q) * NT + j] = acc[m][n][q] * 0.125f;
        }
    }
}

// ---------------------------------------------------------------------------
// K3 v8 = R12-v4 2-phase structure + SOFTWARE-PIPELINED pe loads:
//   each phase-G rtt iteration prefetches rtt+1's pe float4s into registers
//   before computing rtt; at rtt==3 it prefetches subtile s+1's rtt=0, so
//   the post-barrier first iteration's data is already in flight across
//   the phase-S + barrier window.  Every pe load gets >=250cy (intra-phase)
//   or ~1000cy (cross-subtile) of cover instead of being consumed
//   immediately (the v4/v7 pattern: 32 exposed-latency iterations/block).
//   Phase-S identical to R12-v4 (global aff loads).  Arithmetic order
//   byte-identical to R12 -> absmax unchanged.
// ---------------------------------------------------------------------------
__global__ __launch_bounds__(256, 4) void k3_scan(
    const float* __restrict__ pe, const float* __restrict__ iou,
    const float* __restrict__ WGw, const float* __restrict__ WGb,
    const float* __restrict__ aff,
    float* __restrict__ cv, int* __restrict__ ci)
{
    const int ch = blockIdx.x;   // 0..3
    const int it = blockIdx.y;   // 0..127
    const int c  = blockIdx.z;
    const int i0 = it * 8;

    __shared__ float wgl[8][16][33];
    __shared__ float ios[8][33];

    const int t = threadIdx.x;
    const int wave = t >> 6, lane = t & 63;
    const int lg = lane & 15, lk = lane >> 4;
    const int p_i = t >> 5, jq = t & 31;
    const int s_i = t >> 5, s_g = (t >> 1) & 15, s_h = t & 1;

    bf16x8 bh[2], bm[2], bl[2];
    #pragma unroll
    for (int kp = 0; kp < 2; ++kp) {
        float w8[8];
        float4 w0 = *(const float4*)&WGw[lg * 64 + kp * 32 + lk * 8];
        float4 w1 = *(const float4*)&WGw[lg * 64 + kp * 32 + lk * 8 + 4];
        w8[0]=w0.x; w8[1]=w0.y; w8[2]=w0.z; w8[3]=w0.w;
        w8[4]=w1.x; w8[5]=w1.y; w8[6]=w1.z; w8[7]=w1.w;
        split3_8(w8, bh[kp], bm[kp], bl[kp]);
    }
    const float bias = WGb[lg];

    float tv[10]; int tidx[10];
    #pragma unroll
    for (int q = 0; q < 10; ++q) { tv[q] = NEG_BIG; tidx[q] = 0; }

    // prime pipeline: (s=0, rtt=0) pe loads
    float4 p00, p01, p10, p11;
    {
        const int rt0 = wave * 4;
        const float* pr = &pe[(((size_t)c * NT + (i0 + (rt0 >> 1))) * NT
                              + (ch * 256 + ((rt0 & 1) * 16) + lg)) * 64];
        p00 = *(const float4*)&pr[lk * 8];
        p01 = *(const float4*)&pr[lk * 8 + 4];
        p10 = *(const float4*)&pr[32 + lk * 8];
        p11 = *(const float4*)&pr[32 + lk * 8 + 4];
    }

    for (int s = 0; s < 8; ++s) {
        const int j0 = ch * 256 + s * 32;
        // ---- ios staging ----
        {
            const float ia = iou[((size_t)c * NT + (i0 + p_i)) * NT + j0 + jq];
            ios[p_i][jq] = (ia >= 1e-6f) ? 0.f : LOG1E6;
        }
        // ---- phase G: pipelined rtt loop ----
        #pragma unroll 1
        for (int rtt = 0; rtt < 4; ++rtt) {
            // prefetch next (rtt+1, or next subtile's rtt=0; clamp at end)
            const int ns  = (rtt == 3) ? ((s < 7) ? s + 1 : 7) : s;
            const int nr  = (rtt + 1) & 3;
            const int nrt = wave * 4 + nr;
            const float* npr = &pe[(((size_t)c * NT + (i0 + (nrt >> 1))) * NT
                                   + (ch * 256 + ns * 32 + ((nrt & 1) * 16) + lg)) * 64];
            float4 n00 = *(const float4*)&npr[lk * 8];
            float4 n01 = *(const float4*)&npr[lk * 8 + 4];
            float4 n10 = *(const float4*)&npr[32 + lk * 8];
            float4 n11 = *(const float4*)&npr[32 + lk * 8 + 4];
            // compute current rtt from registers
            const int rt = wave * 4 + rtt;
            const int ib = rt >> 1;
            const int jb = (rt & 1) * 16;
            f32x4 acc = {0.f, 0.f, 0.f, 0.f};
            {
                float a8[8];
                a8[0]=p00.x; a8[1]=p00.y; a8[2]=p00.z; a8[3]=p00.w;
                a8[4]=p01.x; a8[5]=p01.y; a8[6]=p01.z; a8[7]=p01.w;
                bf16x8 ah, am, al;
                split3_8(a8, ah, am, al);
                acc = __builtin_amdgcn_mfma_f32_16x16x32_bf16(al, bh[0], acc, 0, 0, 0);
                acc = __builtin_amdgcn_mfma_f32_16x16x32_bf16(ah, bl[0], acc, 0, 0, 0);
                acc = __builtin_amdgcn_mfma_f32_16x16x32_bf16(am, bm[0], acc, 0, 0, 0);
                acc = __builtin_amdgcn_mfma_f32_16x16x32_bf16(am, bh[0], acc, 0, 0, 0);
                acc = __builtin_amdgcn_mfma_f32_16x16x32_bf16(ah, bm[0], acc, 0, 0, 0);
                acc = __builtin_amdgcn_mfma_f32_16x16x32_bf16(ah, bh[0], acc, 0, 0, 0);
            }
            {
                float a8[8];
                a8[0]=p10.x; a8[1]=p10.y; a8[2]=p10.z; a8[3]=p10.w;
                a8[4]=p11.x; a8[5]=p11.y; a8[6]=p11.z; a8[7]=p11.w;
                bf16x8 ah, am, al;
                split3_8(a8, ah, am, al);
                acc = __builtin_amdgcn_mfma_f32_16x16x32_bf16(al, bh[1], acc, 0, 0, 0);
                acc = __builtin_amdgcn_mfma_f32_16x16x32_bf16(ah, bl[1], acc, 0, 0, 0);
                acc = __builtin_amdgcn_mfma_f32_16x16x32_bf16(am, bm[1], acc, 0, 0, 0);
                acc = __builtin_amdgcn_mfma_f32_16x16x32_bf16(am, bh[1], acc, 0, 0, 0);
                acc = __builtin_amdgcn_mfma_f32_16x16x32_bf16(ah, bm[1], acc, 0, 0, 0);
                acc = __builtin_amdgcn_mfma_f32_16x16x32_bf16(ah, bh[1], acc, 0, 0, 0);
            }
            #pragma unroll
            for (int q = 0; q < 4; ++q) {
                const float v = acc[q] + bias;
                wgl[ib][lg][jb + lk * 4 + q] = (v > 1e-6f) ? __logf(v) : LOG1E6;
            }
            // rotate pipeline registers
            p00 = n00; p01 = n01; p10 = n10; p11 = n11;
        }
        __syncthreads();
        // ---- phase S (R12-v4 form: global aff loads) ----
        {
            const float* ar = &aff[(((size_t)(c * GG + s_g)) * NT + (i0 + s_i)) * NT + j0 + s_h * 16];
            const float* wl = &wgl[s_i][s_g][s_h * 16];
            const float* il = &ios[s_i][s_h * 16];
            #pragma unroll
            for (int j4 = 0; j4 < 16; j4 += 4) {
                float4 a4 = *(const float4*)&ar[j4];
                float av[4] = {a4.x, a4.y, a4.z, a4.w};
                #pragma unroll
                for (int q = 0; q < 4; ++q) {
                    const float val = wl[j4 + q] + av[q] + il[j4 + q];
                    if (val > tv[0]) {
                        const int ix = j0 + s_h * 16 + j4 + q;
                        #pragma unroll
                        for (int sl = 0; sl < 10; ++sl) {
                            const bool up   = (sl < 9) ? (val > tv[sl + 1]) : false;
                            const bool here = (val > tv[sl]);
                            const float ntv = up ? tv[sl + 1] : (here ? val : tv[sl]);
                            const int   nti = up ? tidx[sl + 1] : (here ? ix : tidx[sl]);
                            tv[sl] = ntv; tidx[sl] = nti;
                        }
                    }
                }
            }
        }
        __syncthreads();
    }

    float* mv = &wgl[0][0][0];
    int*   mi = (int*)(mv + 1280);
    const int pair = t >> 1;
    if (s_h == 1) {
        #pragma unroll
        for (int q = 0; q < 10; ++q) { mv[pair * 10 + q] = tv[q]; mi[pair * 10 + q] = tidx[q]; }
    }
    __syncthreads();
    if (s_h == 0) {
        for (int q = 9; q >= 0; --q) {
            const float val = mv[pair * 10 + q];
            const int   ix  = mi[pair * 10 + q];
            if (val > tv[0]) {
                #pragma unroll
                for (int sl = 0; sl < 10; ++sl) {
                    const bool up   = (sl < 9) ? (val > tv[sl + 1]) : false;
                    const bool here = (val > tv[sl]);
                    const float ntv = up ? tv[sl + 1] : (here ? val : tv[sl]);
                    const int   nti = up ? tidx[sl + 1] : (here ? ix : tidx[sl]);
                    tv[sl] = ntv; tidx[sl] = nti;
                }
            }
        }
        const size_t base = ((((size_t)c * NT + (i0 + s_i)) * GG + s_g) * 4 + ch) * 10;
        #pragma unroll
        for (int q = 0; q < 10; ++q) { cv[base + q] = tv[q]; ci[base + q] = tidx[q]; }
    }
}

// ---------------------------------------------------------------------------
// K2b2 (unchanged): per-(c,i,g) wave merge + softmax + coalesced V-gather.
// ---------------------------------------------------------------------------
__global__ __launch_bounds__(256) void k2b2_fin(
    const float* __restrict__ cv, const int* __restrict__ ci,
    const float* __restrict__ V, float* __restrict__ y)
{
    const int w    = (blockIdx.x << 2) + (threadIdx.x >> 6);
    const int lane = threadIdx.x & 63;
    const int c = w >> 14;
    const int i = (w >> 4) & (NT - 1);
    const int g = w & 15;

    float tv[10]; int tidx[10];
    #pragma unroll
    for (int q = 0; q < 10; ++q) { tv[q] = NEG_BIG; tidx[q] = 0; }

    const size_t base = (size_t)w * 40;
    for (int chn = 0; chn < 4; ++chn) {
        const float* cvp = &cv[base + chn * 10];
        const int*   cip = &ci[base + chn * 10];
        for (int q = 9; q >= 0; --q) {
            const float val = cvp[q];
            const int   ix  = cip[q];
            if (val > tv[0]) {
                #pragma unroll
                for (int sl = 0; sl < 10; ++sl) {
                    const bool up   = (sl < 9) ? (val > tv[sl + 1]) : false;
                    const bool here = (val > tv[sl]);
                    const float ntv = up ? tv[sl + 1] : (here ? val : tv[sl]);
                    const int   nti = up ? tidx[sl + 1] : (here ? ix : tidx[sl]);
                    tv[sl] = ntv; tidx[sl] = nti;
                }
            }
        }
    }
    const float m = tv[9];
    float wgt[10]; float sm = 0.f;
    #pragma unroll
    for (int q = 0; q < 10; ++q) { wgt[q] = __expf(tv[q] - m); sm += wgt[q]; }
    const float inv = 1.f / sm;
    float o = 0.f;
    #pragma unroll
    for (int q = 0; q < 10; ++q)
        o += (wgt[q] * inv) * V[((size_t)(c * NT + tidx[q])) * DD + g * 64 + lane];
    y[((size_t)i * CD + c) * DD + g * 64 + lane] = o;
}

extern "C" void kernel_launch(void* const* d_in, const int* in_sizes, int n_in,
                              void* d_out, int out_size, void* d_ws, size_t ws_size,
                              hipStream_t stream) {
    (void)in_sizes; (void)n_in; (void)out_size; (void)ws_size;
    const float* f_a = (const float*)d_in[0];
    const float* pe  = (const float*)d_in[1];
    const float* iou = (const float*)d_in[2];
    const float* WGw = (const float*)d_in[3];
    const float* WGb = (const float*)d_in[4];
    const float* WKw = (const float*)d_in[5];
    const float* WKb = (const float*)d_in[6];
    const float* WQw = (const float*)d_in[7];
    const float* WQb = (const float*)d_in[8];
    const float* Cw  = (const float*)d_in[9];
    const float* Cb  = (const float*)d_in[10];
    float* yout = (float*)d_out;

    float* ws  = (float*)d_ws;
    float* V   = ws + (2u << 21);
    float* aff = ws + (3u << 21);
    float* cv  = ws;
    int*   ci  = (int*)(ws + (1u << 21));
    unsigned short* sp = (unsigned short*)(ws + (3u << 21) + (1u << 25));
    const size_t FN = (size_t)CD * NT * DD;   // 2M
    const size_t WN = (size_t)DD * DD;        // 1M
    unsigned short* Fh  = sp;
    unsigned short* Fm  = Fh + FN;
    unsigned short* Fl  = Fm + FN;
    unsigned short* WQh = Fl + FN;
    unsigned short* WQm = WQh + WN;
    unsigned short* WQl = WQm + WN;
    unsigned short* WKh = WQl + WN;
    unsigned short* WKm = WKh + WN;
    unsigned short* WKl = WKm + WN;
    unsigned short* WCh = WKl + WN;
    unsigned short* WCm = WCh + WN;
    unsigned short* WCl = WCm + WN;
    unsigned short* QSh = WCl + WN;
    unsigned short* QSm = QSh + FN;
    unsigned short* QSl = QSm + FN;
    unsigned short* KSh = QSl + FN;
    unsigned short* KSm = KSh + FN;
    unsigned short* KSl = KSm + FN;

    k0_split<<<dim3(512, 4), 256, 0, stream>>>(f_a, WQw, WKw, Cw,
        Fh, Fm, Fl, WQh, WQm, WQl, WKh, WKm, WKl, WCh, WCm, WCl);
    k1_mfma<<<dim3(16, 16, 3), 256, 0, stream>>>(
        Fh, Fm, Fl, WQh, WQm, WQl, WKh, WKm, WKl, WCh, WCm, WCl,
        WQb, WKb, Cb, V, QSh, QSm, QSl, KSh, KSm, KSl);
    k2a_mfma<<<dim3(16, 16, 32), 256, 0, stream>>>(QSh, QSm, QSl, KSh, KSm, KSl, aff);
    k3_scan<<<dim3(4, 128, 2), 256, 0, stream>>>(pe, iou, WGw, WGb, aff, cv, ci);
    k2b2_fin<<<8192, 256, 0, stream>>>(cv, ci, V, yout);
}